// Round 9
// baseline (121.993 us; speedup 1.0000x reference)
//
#include <hip/hip_runtime.h>
#include <cmath>

#define B_   2
#define C_   256
#define HC_  128
#define DC_  3
#define H_   48
#define W_   48
#define HW_  (H_ * W_)      // 2304
#define NP_  (B_ * HW_)     // 4608
#define K_   (DC_ * 49)     // 147
#define GW   64             // padded g width (col = x+3, 16B-aligned rows)

typedef unsigned short ush;
typedef __attribute__((ext_vector_type(8))) short bf16x8;
typedef __attribute__((ext_vector_type(8))) unsigned short ush8x;
typedef __attribute__((ext_vector_type(4))) float f32x4;
typedef __attribute__((ext_vector_type(4))) unsigned u32x4;

__device__ inline ush f2bf(float f) {
    union { float f; unsigned u; } v; v.f = f;
    unsigned r = v.u + 0x7FFF + ((v.u >> 16) & 1);
    return (ush)(r >> 16);
}
__device__ inline float bf2f(ush h) {
    union { unsigned u; float f; } v; v.u = ((unsigned)h) << 16;
    return v.f;
}
__device__ inline unsigned packhl(float f) {
    ush h = f2bf(f);
    ush l = f2bf(f - bf2f(h));
    return (unsigned)h | ((unsigned)l << 16);
}

// ---------------------------------------------------------------------------
// 0) split weights into bf16 hi/lo planes.
__global__ __launch_bounds__(256) void split_w_kernel(
    const float* __restrict__ psi_w, const float* __restrict__ g_w,
    const float* __restrict__ theta_w, const float* __restrict__ Ww,
    ush* __restrict__ WpgH, ush* __restrict__ WpgL,
    ush* __restrict__ WqH, ush* __restrict__ WqL,
    ush* __restrict__ WwH, ush* __restrict__ WwL)
{
    int idx = (blockIdx.x * 256 + threadIdx.x) * 4;   // grid 128 -> 131072 elems
    float4 v;
    ush *dH, *dL;
    if (idx < 65536) {
        v = *(const float4*)(idx < 32768 ? psi_w + idx : g_w + (idx - 32768));
        dH = WpgH + idx; dL = WpgL + idx;
    } else if (idx < 98304) {
        v = *(const float4*)(theta_w + idx - 65536);
        dH = WqH + idx - 65536; dL = WqL + idx - 65536;
    } else {
        v = *(const float4*)(Ww + idx - 98304);
        dH = WwH + idx - 98304; dL = WwL + idx - 98304;
    }
    ushort4 h, l;
    h.x = f2bf(v.x); l.x = f2bf(v.x - bf2f(h.x));
    h.y = f2bf(v.y); l.y = f2bf(v.y - bf2f(h.y));
    h.z = f2bf(v.z); l.z = f2bf(v.z - bf2f(h.z));
    h.w = f2bf(v.w); l.w = f2bf(v.w - bf2f(h.w));
    *(ushort4*)dH = h; *(ushort4*)dL = l;
}

// ---------------------------------------------------------------------------
// 0b) transpose + bf16-split: ctx -> ctxT [b][d][hw][c] hi/lo, x -> xT hi/lo.
__global__ __launch_bounds__(256) void xpose_kernel(
    const float* __restrict__ ctx, const float* __restrict__ x,
    ush* __restrict__ ctxTH, ush* __restrict__ ctxTL,
    ush* __restrict__ xTH, ush* __restrict__ xTL)
{
    __shared__ float T[64][65];
    int id = blockIdx.x;
    const float* src;
    ush *dH, *dL;
    size_t rowStride;
    if (id < 864) {
        int ct = id & 3, pt = (id >> 2) % 36, bd = id / 144;
        int b = bd / 3, d = bd % 3;
        int c0 = ct * 64, p0 = pt * 64;
        src = ctx + ((size_t)(b * 256 + c0) * 3 + d) * HW_ + p0;
        rowStride = 3 * HW_;
        size_t ob = ((size_t)(b * 3 + d) * HW_ + p0) * 256 + c0;
        dH = ctxTH + ob; dL = ctxTL + ob;
    } else {
        int id2 = id - 864;
        int ct = id2 & 3, pt = (id2 >> 2) % 36, b = id2 / 144;
        int c0 = ct * 64, p0 = pt * 64;
        src = x + (size_t)(b * 256 + c0) * HW_ + p0;
        rowStride = HW_;
        size_t ob = ((size_t)b * HW_ + p0) * 256 + c0;
        dH = xTH + ob; dL = xTL + ob;
    }
    int t = threadIdx.x;
    int cl = t >> 4, p4 = (t & 15) * 4;
    #pragma unroll
    for (int r = 0; r < 4; ++r) {
        int c = cl + r * 16;
        float4 v = *(const float4*)(src + (size_t)c * rowStride + p4);
        T[c][p4] = v.x; T[c][p4 + 1] = v.y; T[c][p4 + 2] = v.z; T[c][p4 + 3] = v.w;
    }
    __syncthreads();
    int pl = t >> 2, ch = t & 3;
    #pragma unroll
    for (int s = 0; s < 2; ++s) {
        int c8 = (ch + s * 4) * 8;
        ush8x vh, vl;
        #pragma unroll
        for (int i = 0; i < 8; ++i) {
            float f = T[c8 + i][pl];
            ush hh = f2bf(f);
            vh[i] = hh;
            vl[i] = f2bf(f - bf2f(hh));
        }
        *(ush8x*)(dH + (size_t)pl * 256 + c8) = vh;
        *(ush8x*)(dL + (size_t)pl * 256 + c8) = vl;
    }
}

// ---------------------------------------------------------------------------
// 1) LDS-free MFMA projection, occupancy-first: wave = 16px x 32out,
//    per ks: 6 loads + 6 MFMAs into 2 acc chains. 2016 blocks (~8/CU) so
//    ~8 waves/SIMD hide L2/L3 latency. Epilogue: LDS transpose -> 16B stores.
__global__ __launch_bounds__(256, 8) void proj3_kernel(
    const ush* __restrict__ WpgH, const ush* __restrict__ WpgL,
    const ush* __restrict__ WqH, const ush* __restrict__ WqL,
    const ush* __restrict__ ctxTH, const ush* __restrict__ ctxTL,
    const ush* __restrict__ xTH, const ush* __restrict__ xTL,
    ush* __restrict__ psiH, ush* __restrict__ psiL,
    ush* __restrict__ gtmp, ush* __restrict__ qH, ush* __restrict__ qL)
{
    __shared__ unsigned T[32][68];      // [px][o] packed (hi | lo<<16), padded

    int bid = blockIdx.x;
    int swz = (bid & 7) * 252 + (bid >> 3);   // 2016 = 8 * 252, XCD-contiguous
    int t = threadIdx.x, w = t >> 6, l = t & 63, lc = l & 15, grp = l >> 4;
    int mode, b, d, pxBase, otg;
    const ush *XH, *XL, *WH, *WL;
    if (swz < 1728) {
        mode = 0; otg = swz & 3;
        int rest = swz >> 2;               // 0..431
        int pxt = rest % 72, bd = rest / 72;
        b = bd / 3; d = bd % 3;
        pxBase = pxt * 32;
        size_t xb = (size_t)(b * 3 + d) * HW_ * 256;
        XH = ctxTH + xb; XL = ctxTL + xb;
        WH = WpgH; WL = WpgL;
    } else {
        mode = 1;
        int id2 = swz - 1728; otg = id2 & 1;
        int rest = id2 >> 1;               // 0..143
        int pxt = rest % 72; b = rest / 72; d = 0;
        pxBase = pxt * 32;
        size_t xb = (size_t)b * HW_ * 256;
        XH = xTH + xb; XL = xTL + xb;
        WH = WqH; WL = WqL;
    }
    int pxHalf = (w & 1) * 16;
    int outHalf = (w >> 1) * 32;

    const ush* xr  = XH + (size_t)(pxBase + pxHalf + lc) * 256 + grp * 8;
    const ush* xrL = XL + (size_t)(pxBase + pxHalf + lc) * 256 + grp * 8;
    const ush* wa  = WH + (size_t)(otg * 64 + outHalf + lc) * 256 + grp * 8;
    const ush* waL = WL + (size_t)(otg * 64 + outHalf + lc) * 256 + grp * 8;

    f32x4 acc0 = {0.f, 0.f, 0.f, 0.f};
    f32x4 acc1 = {0.f, 0.f, 0.f, 0.f};

    #pragma unroll
    for (int ks = 0; ks < 8; ++ks) {
        bf16x8 bh  = *(const bf16x8*)(xr  + ks * 32);
        bf16x8 bl  = *(const bf16x8*)(xrL + ks * 32);
        bf16x8 a0h = *(const bf16x8*)(wa  + ks * 32);
        bf16x8 a0l = *(const bf16x8*)(waL + ks * 32);
        bf16x8 a1h = *(const bf16x8*)(wa  + 4096 + ks * 32);
        bf16x8 a1l = *(const bf16x8*)(waL + 4096 + ks * 32);
        acc0 = __builtin_amdgcn_mfma_f32_16x16x32_bf16(a0h, bh, acc0, 0, 0, 0);
        acc1 = __builtin_amdgcn_mfma_f32_16x16x32_bf16(a1h, bh, acc1, 0, 0, 0);
        acc0 = __builtin_amdgcn_mfma_f32_16x16x32_bf16(a0h, bl, acc0, 0, 0, 0);
        acc1 = __builtin_amdgcn_mfma_f32_16x16x32_bf16(a1h, bl, acc1, 0, 0, 0);
        acc0 = __builtin_amdgcn_mfma_f32_16x16x32_bf16(a0l, bh, acc0, 0, 0, 0);
        acc1 = __builtin_amdgcn_mfma_f32_16x16x32_bf16(a1l, bh, acc1, 0, 0, 0);
    }

    // pack accs into LDS: T[px_local][o_local], o_local = outHalf + oi*16 + grp*4 + r
    {
        u32x4 pv;
        pv[0] = packhl(acc0[0]); pv[1] = packhl(acc0[1]);
        pv[2] = packhl(acc0[2]); pv[3] = packhl(acc0[3]);
        *(u32x4*)&T[pxHalf + lc][outHalf + grp * 4] = pv;
        pv[0] = packhl(acc1[0]); pv[1] = packhl(acc1[1]);
        pv[2] = packhl(acc1[2]); pv[3] = packhl(acc1[3]);
        *(u32x4*)&T[pxHalf + lc][outHalf + 16 + grp * 4] = pv;
    }
    __syncthreads();

    if (mode == 1 || otg < 2) {
        // psi / q readback: [px][8 consecutive h] -> 16B hi + 16B lo stores
        ush* PH = (mode == 0) ? psiH : qH;
        ush* PL = (mode == 0) ? psiL : qL;
        int pxl = t >> 3, ch = t & 7;
        u32x4 v0 = *(const u32x4*)&T[pxl][ch * 8];
        u32x4 v1 = *(const u32x4*)&T[pxl][ch * 8 + 4];
        ush8x hi, lo;
        #pragma unroll
        for (int i = 0; i < 4; ++i) {
            hi[i] = (ush)(v0[i] & 0xffffu); lo[i] = (ush)(v0[i] >> 16);
            hi[4 + i] = (ush)(v1[i] & 0xffffu); lo[4 + i] = (ush)(v1[i] >> 16);
        }
        int pix = pxBase + pxl;
        size_t base;
        if (mode == 0)
            base = ((size_t)(b * DC_ + d) * HW_ + pix) * HC_ + otg * 64 + ch * 8;
        else
            base = ((size_t)b * HW_ + pix) * HC_ + otg * 64 + ch * 8;
        *(ush8x*)&PH[base] = hi;
        *(ush8x*)&PL[base] = lo;
    } else {
        // g readback: [o][8 consecutive px] -> 16B stores into unpadded gtmp
        int ol = t >> 2, pg = t & 3;
        ush8x hv;
        #pragma unroll
        for (int i = 0; i < 8; ++i)
            hv[i] = (ush)(T[pg * 8 + i][ol] & 0xffffu);
        int og = (otg - 2) * 64 + ol;
        int pxg = pxBase + pg * 8;              // 8-px groups never straddle y
        int yy = pxg / W_, xx = pxg - yy * W_;
        *(ush8x*)&gtmp[(((size_t)(b * HC_ + og) * DC_ + d) * H_ + yy) * W_ + xx] = hv;
    }
}

// ---------------------------------------------------------------------------
// 1b) pad: gtmp rows (48) -> gB rows (64) with +3 shift and edge replication.
__global__ __launch_bounds__(256) void pad2_kernel(
    const ush* __restrict__ gtmp, ush* __restrict__ gB)
{
    __shared__ ush R[32][48];
    int blk = blockIdx.x, t = threadIdx.x;
    int r = t >> 3, ch = t & 7;
    size_t row = (size_t)blk * 32 + r;
    if (ch < 6)
        *(ush8x*)&R[r][ch * 8] = *(const ush8x*)&gtmp[row * W_ + ch * 8];
    __syncthreads();
    ush8x o;
    #pragma unroll
    for (int i = 0; i < 8; ++i) {
        int x = ch * 8 + i - 3;
        x = min(max(x, 0), W_ - 1);
        o[i] = R[r][x];
    }
    *(ush8x*)&gB[row * GW + ch * 8] = o;
}

// ---------------------------------------------------------------------------
// 2) MFMA band-GEMM attention with compensated-bf16 scores (unchanged).
__global__ __launch_bounds__(512) void attn_mfma_kernel(
    const ush* __restrict__ qHp, const ush* __restrict__ qLp,
    const ush* __restrict__ psiHp, const ush* __restrict__ psiLp,
    const ush* __restrict__ g,
    ush* __restrict__ yH, ush* __restrict__ yL)
{
    __shared__ float S[147 * 17];

    int bid = blockIdx.x;
    int tile = (bid & 7) * 36 + (bid >> 3);   // XCD-contiguous pixel rows
    int b = tile / 144;
    int tr = tile - b * 144;
    int y0 = tr / 3;
    int x0 = (tr % 3) * 16;

    int t = threadIdx.x;
    int w = t >> 6;
    int l = t & 63;
    int lc = l & 15;
    int grp = l >> 4;
    int pixBase = b * HW_ + y0 * W_ + x0;

    const ush* qrowH = qHp + (size_t)(pixBase + lc) * HC_ + grp * 8;
    const ush* qrowL = qLp + (size_t)(pixBase + lc) * HC_ + grp * 8;
    bf16x8 qh[4], ql[4];
    #pragma unroll
    for (int ks = 0; ks < 4; ++ks) {
        qh[ks] = *(const bf16x8*)(qrowH + ks * 32);
        ql[ks] = *(const bf16x8*)(qrowL + ks * 32);
    }

    // ---- scores ----
    for (int idx = w; idx < 21; idx += 8) {
        int d = idx / 7, i = idx - 7 * d;
        int ry = min(max(y0 + i - 3, 0), H_ - 1);
        size_t rowOff = ((size_t)(b * DC_ + d) * HW_ + ry * W_) * HC_;
        const ush* psiRowH = psiHp + rowOff;
        const ush* psiRowL = psiLp + rowOff;
        #pragma unroll
        for (int f = 0; f < 2; ++f) {
            int c = f * 16 + lc;
            int px = min(max(x0 + c - 3, 0), W_ - 1);
            const ush* bpH = psiRowH + (size_t)px * HC_ + grp * 8;
            const ush* bpL = psiRowL + (size_t)px * HC_ + grp * 8;
            f32x4 acc = {0.f, 0.f, 0.f, 0.f};
            #pragma unroll
            for (int ks = 0; ks < 4; ++ks) {
                bf16x8 ph = *(const bf16x8*)(bpH + ks * 32);
                bf16x8 pl = *(const bf16x8*)(bpL + ks * 32);
                acc = __builtin_amdgcn_mfma_f32_16x16x32_bf16(qh[ks], ph, acc, 0, 0, 0);
                acc = __builtin_amdgcn_mfma_f32_16x16x32_bf16(qh[ks], pl, acc, 0, 0, 0);
                acc = __builtin_amdgcn_mfma_f32_16x16x32_bf16(ql[ks], ph, acc, 0, 0, 0);
            }
            #pragma unroll
            for (int r = 0; r < 4; ++r) {
                int p = grp * 4 + r;
                int j = c - p;
                if (j >= 0 && j < 7) S[(idx * 7 + j) * 17 + p] = acc[r];
            }
        }
    }
    __syncthreads();

    // ---- softmax ----
    #pragma unroll
    for (int pi = 0; pi < 2; ++pi) {
        int p = w * 2 + pi;
        float s0 = S[l * 17 + p];
        float s1 = S[(64 + l) * 17 + p];
        float s2 = (l + 128 < K_) ? S[(128 + l) * 17 + p] : -1e30f;
        float m = fmaxf(fmaxf(s0, s1), s2);
        #pragma unroll
        for (int off = 32; off; off >>= 1) m = fmaxf(m, __shfl_xor(m, off));
        float e0 = __expf(s0 - m), e1 = __expf(s1 - m), e2 = __expf(s2 - m);
        float sum = e0 + e1 + e2;
        #pragma unroll
        for (int off = 32; off; off >>= 1) sum += __shfl_xor(sum, off);
        float inv = 1.0f / sum;
        S[l * 17 + p] = e0 * inv;
        S[(64 + l) * 17 + p] = e1 * inv;
        if (l + 128 < K_) S[(128 + l) * 17 + p] = e2 * inv;
    }
    __syncthreads();

    // ---- PV ----
    int hB = w * 16 + lc;
    f32x4 acc = {0.f, 0.f, 0.f, 0.f};
    for (int idx = 0; idx < 21; ++idx) {
        int d = idx / 7, i = idx - 7 * d;
        int ry = min(max(y0 + i - 3, 0), H_ - 1);
        unsigned au[4];
        #pragma unroll
        for (int rr = 0; rr < 4; ++rr) {
            int k0 = grp * 8 + rr * 2;
            int j0 = k0 - lc, j1 = k0 + 1 - lc;
            float v0 = (j0 >= 0 && j0 < 7) ? S[(idx * 7 + j0) * 17 + lc] : 0.f;
            float v1 = (j1 >= 0 && j1 < 7) ? S[(idx * 7 + j1) * 17 + lc] : 0.f;
            au[rr] = (unsigned)f2bf(v0) | ((unsigned)f2bf(v1) << 16);
        }
        union { unsigned u[4]; bf16x8 v; } af;
        af.u[0] = au[0]; af.u[1] = au[1]; af.u[2] = au[2]; af.u[3] = au[3];
        const ush* gb = g
            + (((size_t)(b * HC_ + hB) * DC_ + d) * H_ + ry) * GW + x0 + grp * 8;
        bf16x8 bg = *(const bf16x8*)gb;
        acc = __builtin_amdgcn_mfma_f32_16x16x32_bf16(af.v, bg, acc, 0, 0, 0);
    }
    #pragma unroll
    for (int r = 0; r < 4; ++r) {
        int p = grp * 4 + r;
        size_t o = (size_t)(pixBase + p) * HC_ + hB;
        float v = acc[r];
        ush hh = f2bf(v);
        yH[o] = hh;
        yL[o] = f2bf(v - bf2f(hh));
    }
}

// ---------------------------------------------------------------------------
// 3) wy = W_w @ y via MFMA, compensated bf16, direct global loads (unchanged).
__global__ __launch_bounds__(512) void wy_mfma_kernel(
    const ush* __restrict__ WwH, const ush* __restrict__ WwL,
    const ush* __restrict__ yHp, const ush* __restrict__ yLp,
    float* __restrict__ wyO)
{
    int blk = blockIdx.x;              // 144
    int t = threadIdx.x;
    int l = t & 63, w = t >> 6;
    int lc = l & 15, grp = l >> 4;
    int pxg = blk * 32 + (w & 1) * 16 + lc;
    int b = pxg / HW_;
    int p = pxg - b * HW_;

    bf16x8 bH[4], bL[4];
    #pragma unroll
    for (int ks = 0; ks < 4; ++ks) {
        bH[ks] = *(const bf16x8*)&yHp[(size_t)pxg * HC_ + ks * 32 + grp * 8];
        bL[ks] = *(const bf16x8*)&yLp[(size_t)pxg * HC_ + ks * 32 + grp * 8];
    }

    int otBase = (w >> 1) * 4;
    #pragma unroll
    for (int oi = 0; oi < 4; ++oi) {
        int ot = otBase + oi;
        const ush* wrH = WwH + (size_t)(ot * 16 + lc) * HC_ + grp * 8;
        const ush* wrL = WwL + (size_t)(ot * 16 + lc) * HC_ + grp * 8;
        f32x4 acc = {0.f, 0.f, 0.f, 0.f};
        #pragma unroll
        for (int ks = 0; ks < 4; ++ks) {
            bf16x8 aH = *(const bf16x8*)(wrH + ks * 32);
            bf16x8 aL = *(const bf16x8*)(wrL + ks * 32);
            acc = __builtin_amdgcn_mfma_f32_16x16x32_bf16(aH, bH[ks], acc, 0, 0, 0);
            acc = __builtin_amdgcn_mfma_f32_16x16x32_bf16(aH, bL[ks], acc, 0, 0, 0);
            acc = __builtin_amdgcn_mfma_f32_16x16x32_bf16(aL, bH[ks], acc, 0, 0, 0);
        }
        int o0 = ot * 16 + grp * 4;
        #pragma unroll
        for (int r2 = 0; r2 < 4; ++r2)
            wyO[(size_t)(b * C_ + o0 + r2) * HW_ + p] = acc[r2];
    }
}

// ---------------------------------------------------------------------------
// 4) BN batch stats per channel -> folded scale/shift.  grid = 256
__global__ __launch_bounds__(256) void bn_stats_kernel(
    const float* __restrict__ wy, const float* __restrict__ gamma,
    const float* __restrict__ beta, float2* __restrict__ stats)
{
    int o = blockIdx.x;
    int tid = threadIdx.x;
    float s = 0.f, s2 = 0.f;
    for (int idx = tid; idx < NP_; idx += 256) {
        int b = idx / HW_;
        int p = idx - b * HW_;
        float v = wy[(size_t)(b * C_ + o) * HW_ + p];
        s += v;
        s2 = fmaf(v, v, s2);
    }
    #pragma unroll
    for (int off = 32; off; off >>= 1) {
        s  += __shfl_xor(s, off);
        s2 += __shfl_xor(s2, off);
    }
    __shared__ float ls[4], ls2[4];
    int wv = tid >> 6, lane = tid & 63;
    if (lane == 0) { ls[wv] = s; ls2[wv] = s2; }
    __syncthreads();
    if (tid == 0) {
        float S  = ls[0] + ls[1] + ls[2] + ls[3];
        float S2 = ls2[0] + ls2[1] + ls2[2] + ls2[3];
        float mean = S / (float)NP_;
        float var = fmaxf(S2 / (float)NP_ - mean * mean, 0.f);
        float rstd = rsqrtf(var + 1e-5f);
        float sc = gamma[o] * rstd;
        stats[o] = make_float2(sc, beta[o] - mean * sc);
    }
}

// ---------------------------------------------------------------------------
// 5) z = x + wy*scale + shift
__global__ __launch_bounds__(256) void final_kernel(
    const float* __restrict__ x, const float* __restrict__ wy,
    const float2* __restrict__ stats, float* __restrict__ out)
{
    int idx = blockIdx.x * 256 + threadIdx.x;
    int e0 = idx * 4;
    int c = (e0 / HW_) & (C_ - 1);
    float2 st = stats[c];
    float4 xv = *(const float4*)(x + e0);
    float4 wv = *(const float4*)(wy + e0);
    float4 o;
    o.x = fmaf(wv.x, st.x, xv.x + st.y);
    o.y = fmaf(wv.y, st.x, xv.y + st.y);
    o.z = fmaf(wv.z, st.x, xv.z + st.y);
    o.w = fmaf(wv.w, st.x, xv.w + st.y);
    *(float4*)(out + e0) = o;
}

extern "C" void kernel_launch(void* const* d_in, const int* in_sizes, int n_in,
                              void* d_out, int out_size, void* d_ws, size_t ws_size,
                              hipStream_t stream) {
    const float* x       = (const float*)d_in[0];
    const float* ctx     = (const float*)d_in[1];
    const float* theta_w = (const float*)d_in[2];
    const float* psi_w   = (const float*)d_in[3];
    const float* g_w     = (const float*)d_in[4];
    const float* W_w     = (const float*)d_in[5];
    // d_in[6] = W_b: unused, cancels exactly under training-mode BN
    const float* gamma   = (const float*)d_in[7];
    const float* beta    = (const float*)d_in[8];
    float* out = (float*)d_out;

    ush* ws = (ush*)d_ws;
    ush* qH    = ws;                     // 589824
    ush* qL    = qH + 589824;
    ush* psiH  = qL + 589824;            // 1769472
    ush* psiL  = psiH + 1769472;
    ush* gB    = psiL + 1769472;         // 2359296  [B,128,3,48,64] padded
    ush* gtmp  = gB + 2359296;           // 3538944  [B,128,3,48,48] unpadded
    ush* WpgH  = gtmp + 3538944;         // 65536
    ush* WpgL  = WpgH + 65536;
    ush* WqH   = WpgL + 65536;           // 32768
    ush* WqL   = WqH + 32768;
    ush* WwH   = WqL + 32768;            // 32768
    ush* WwL   = WwH + 32768;
    ush* ctxTH = WwL + 32768;            // 3538944
    ush* ctxTL = ctxTH + 3538944;
    ush* xTH   = ctxTL + 3538944;        // 1179648
    ush* xTL   = xTH + 1179648;
    float2* stats = (float2*)(xTL + 1179648);
    // aliases (stream-ordered single-call lifetimes, deterministic each call):
    float* wyB = (float*)ctxTH;          // 1179648 f32 <= ctxT region
    ush* yH = xTH;                       // y produced after proj consumed xT
    ush* yL = xTH + 589824;

    split_w_kernel<<<dim3(128), 256, 0, stream>>>(psi_w, g_w, theta_w, W_w,
                                                  WpgH, WpgL, WqH, WqL, WwH, WwL);
    xpose_kernel<<<dim3(1152), 256, 0, stream>>>(ctx, x, ctxTH, ctxTL, xTH, xTL);
    proj3_kernel<<<dim3(2016), 256, 0, stream>>>(WpgH, WpgL, WqH, WqL,
                                                 ctxTH, ctxTL, xTH, xTL,
                                                 psiH, psiL, gtmp, qH, qL);
    pad2_kernel<<<dim3(1152), 256, 0, stream>>>(gtmp, gB);
    attn_mfma_kernel<<<dim3(288), 512, 0, stream>>>(qH, qL, psiH, psiL, gB, yH, yL);
    wy_mfma_kernel<<<dim3(144), 512, 0, stream>>>(WwH, WwL, yH, yL, wyB);
    bn_stats_kernel<<<dim3(C_), 256, 0, stream>>>(wyB, gamma, beta, stats);
    final_kernel<<<dim3(B_ * C_ * HW_ / 4 / 256), 256, 0, stream>>>(x, wyB, stats, out);
}

// Round 10
// 87.915 us; speedup vs baseline: 1.3876x; 1.3876x over previous
//
#include <hip/hip_runtime.h>
#include <cmath>

#define B_   2
#define C_   256
#define HC_  128
#define DC_  3
#define H_   48
#define W_   48
#define HW_  (H_ * W_)      // 2304
#define NP_  (B_ * HW_)     // 4608
#define K_   (DC_ * 49)     // 147
#define GW   64             // padded g width (col = x+3, 16B-aligned rows)

typedef unsigned short ush;
typedef __attribute__((ext_vector_type(8))) short bf16x8;
typedef __attribute__((ext_vector_type(8))) unsigned short ush8x;
typedef __attribute__((ext_vector_type(4))) float f32x4;
typedef __attribute__((ext_vector_type(4))) unsigned u32x4;

__device__ inline ush f2bf(float f) {
    union { float f; unsigned u; } v; v.f = f;
    unsigned r = v.u + 0x7FFF + ((v.u >> 16) & 1);
    return (ush)(r >> 16);
}
__device__ inline float bf2f(ush h) {
    union { unsigned u; float f; } v; v.u = ((unsigned)h) << 16;
    return v.f;
}
__device__ inline unsigned packhl(float f) {
    ush h = f2bf(f);
    ush l = f2bf(f - bf2f(h));
    return (unsigned)h | ((unsigned)l << 16);
}
__device__ __forceinline__ void gload16(const void* g, void* l) {
    __builtin_amdgcn_global_load_lds(
        (const __attribute__((address_space(1))) unsigned*)g,
        (__attribute__((address_space(3))) unsigned*)l, 16, 0, 0);
}

// ---------------------------------------------------------------------------
// 0) split weights into bf16 hi/lo planes.
__global__ __launch_bounds__(256) void split_w_kernel(
    const float* __restrict__ psi_w, const float* __restrict__ g_w,
    const float* __restrict__ theta_w, const float* __restrict__ Ww,
    ush* __restrict__ WpgH, ush* __restrict__ WpgL,
    ush* __restrict__ WqH, ush* __restrict__ WqL,
    ush* __restrict__ WwH, ush* __restrict__ WwL)
{
    int idx = (blockIdx.x * 256 + threadIdx.x) * 4;   // grid 128 -> 131072 elems
    float4 v;
    ush *dH, *dL;
    if (idx < 65536) {
        v = *(const float4*)(idx < 32768 ? psi_w + idx : g_w + (idx - 32768));
        dH = WpgH + idx; dL = WpgL + idx;
    } else if (idx < 98304) {
        v = *(const float4*)(theta_w + idx - 65536);
        dH = WqH + idx - 65536; dL = WqL + idx - 65536;
    } else {
        v = *(const float4*)(Ww + idx - 98304);
        dH = WwH + idx - 98304; dL = WwL + idx - 98304;
    }
    ushort4 h, l;
    h.x = f2bf(v.x); l.x = f2bf(v.x - bf2f(h.x));
    h.y = f2bf(v.y); l.y = f2bf(v.y - bf2f(h.y));
    h.z = f2bf(v.z); l.z = f2bf(v.z - bf2f(h.z));
    h.w = f2bf(v.w); l.w = f2bf(v.w - bf2f(h.w));
    *(ushort4*)dH = h; *(ushort4*)dL = l;
}

// ---------------------------------------------------------------------------
// 0b) transpose + bf16-split: ctx -> ctxT [b][d][hw][c] hi/lo, x -> xT hi/lo.
__global__ __launch_bounds__(256) void xpose_kernel(
    const float* __restrict__ ctx, const float* __restrict__ x,
    ush* __restrict__ ctxTH, ush* __restrict__ ctxTL,
    ush* __restrict__ xTH, ush* __restrict__ xTL)
{
    __shared__ float T[64][65];
    int id = blockIdx.x;
    const float* src;
    ush *dH, *dL;
    size_t rowStride;
    if (id < 864) {
        int ct = id & 3, pt = (id >> 2) % 36, bd = id / 144;
        int b = bd / 3, d = bd % 3;
        int c0 = ct * 64, p0 = pt * 64;
        src = ctx + ((size_t)(b * 256 + c0) * 3 + d) * HW_ + p0;
        rowStride = 3 * HW_;
        size_t ob = ((size_t)(b * 3 + d) * HW_ + p0) * 256 + c0;
        dH = ctxTH + ob; dL = ctxTL + ob;
    } else {
        int id2 = id - 864;
        int ct = id2 & 3, pt = (id2 >> 2) % 36, b = id2 / 144;
        int c0 = ct * 64, p0 = pt * 64;
        src = x + (size_t)(b * 256 + c0) * HW_ + p0;
        rowStride = HW_;
        size_t ob = ((size_t)b * HW_ + p0) * 256 + c0;
        dH = xTH + ob; dL = xTL + ob;
    }
    int t = threadIdx.x;
    int cl = t >> 4, p4 = (t & 15) * 4;
    #pragma unroll
    for (int r = 0; r < 4; ++r) {
        int c = cl + r * 16;
        float4 v = *(const float4*)(src + (size_t)c * rowStride + p4);
        T[c][p4] = v.x; T[c][p4 + 1] = v.y; T[c][p4 + 2] = v.z; T[c][p4 + 3] = v.w;
    }
    __syncthreads();
    int pl = t >> 2, ch = t & 3;
    #pragma unroll
    for (int s = 0; s < 2; ++s) {
        int c8 = (ch + s * 4) * 8;
        ush8x vh, vl;
        #pragma unroll
        for (int i = 0; i < 8; ++i) {
            float f = T[c8 + i][pl];
            ush hh = f2bf(f);
            vh[i] = hh;
            vl[i] = f2bf(f - bf2f(hh));
        }
        *(ush8x*)(dH + (size_t)pl * 256 + c8) = vh;
        *(ush8x*)(dL + (size_t)pl * 256 + c8) = vl;
    }
}

// ---------------------------------------------------------------------------
// 1) proj4: m97-style MFMA GEMM. Block = 64out x 64px, K=256 in 4 steps of 64.
//    Per step: 4 waves cooperatively global_load_lds A-hi/A-lo/B-hi/B-lo
//    (1KB per issue, XOR-by-row kgroup swizzle via per-lane global address),
//    barrier, then each wave runs 24 MFMAs from LDS (ds_read_b128).
//    Compensated bf16: acc = Ah*Bh + Ah*Bl + Al*Bh.
__global__ __launch_bounds__(256) void proj4_kernel(
    const ush* __restrict__ WpgH, const ush* __restrict__ WpgL,
    const ush* __restrict__ WqH, const ush* __restrict__ WqL,
    const ush* __restrict__ ctxTH, const ush* __restrict__ ctxTL,
    const ush* __restrict__ xTH, const ush* __restrict__ xTL,
    ush* __restrict__ psiH, ush* __restrict__ psiL,
    ush* __restrict__ gtmp, ush* __restrict__ qH, ush* __restrict__ qL)
{
    __shared__ __align__(16) unsigned char LB[32768];  // A-H|A-L|B-H|B-L 8KB each

    int bid = blockIdx.x;
    int swz = (bid & 7) * 126 + (bid >> 3);   // 1008 = 8*126, XCD-contiguous
    int t = threadIdx.x, w = t >> 6, l = t & 63, lc = l & 15, grp = l >> 4;
    int mode, b, d, pxBase, otg;
    const ush *XH, *XL, *WH, *WL;
    if (swz < 864) {
        mode = 0; otg = swz & 3;               // 0,1: psi  2,3: g
        int rest = swz >> 2;                   // 0..215
        int pxt = rest % 36, bd = rest / 36;
        b = bd / 3; d = bd % 3;
        pxBase = pxt * 64;
        size_t xb = (size_t)(b * 3 + d) * HW_ * 256;
        XH = ctxTH + xb; XL = ctxTL + xb;
        WH = WpgH; WL = WpgL;
    } else {
        mode = 1;
        int id2 = swz - 864; otg = id2 & 1;
        int rest = id2 >> 1;                   // 0..71
        int pxt = rest % 36; b = rest / 36; d = 0;
        pxBase = pxt * 64;
        size_t xb = (size_t)b * HW_ * 256;
        XH = xTH + xb; XL = xTL + xb;
        WH = WqH; WL = WqL;
    }

    // staging role per wave: 0=A-H 1=A-L 2=B-H 3=B-L
    const ush* GSRC = (w == 0) ? WH : (w == 1) ? WL : (w == 2) ? XH : XL;
    int rowBase = (w < 2) ? (otg * 64) : pxBase;
    int r8 = l >> 3;                  // row within 8-row group
    int kg = (l & 7) ^ r8;            // fetched kgroup (slot = l&7, swizzle)
    unsigned char* ldsPlane = LB + w * 8192;

    f32x4 acc0 = {0,0,0,0}, acc1 = {0,0,0,0}, acc2 = {0,0,0,0}, acc3 = {0,0,0,0};

    for (int kst = 0; kst < 4; ++kst) {
        __syncthreads();              // previous tile fully consumed
        #pragma unroll
        for (int wl = 0; wl < 8; ++wl) {
            int row = rowBase + wl * 8 + r8;
            gload16(GSRC + (size_t)row * 256 + kst * 64 + kg * 8,
                    ldsPlane + wl * 1024);
        }
        __syncthreads();              // compiler drains vmcnt before barrier

        #pragma unroll
        for (int ksub = 0; ksub < 2; ++ksub) {
            int sw = ((ksub * 4 + grp) ^ (lc & 7)) << 4;
            int brow = w * 16 + lc;
            bf16x8 bh = *(const bf16x8*)(LB + 16384 + brow * 128 + sw);
            bf16x8 bl = *(const bf16x8*)(LB + 24576 + brow * 128 + sw);
            #pragma unroll
            for (int ot = 0; ot < 4; ++ot) {
                int arow = ot * 16 + lc;
                bf16x8 ah = *(const bf16x8*)(LB +        arow * 128 + sw);
                bf16x8 al = *(const bf16x8*)(LB + 8192 + arow * 128 + sw);
                f32x4 a = (ot == 0) ? acc0 : (ot == 1) ? acc1 : (ot == 2) ? acc2 : acc3;
                a = __builtin_amdgcn_mfma_f32_16x16x32_bf16(ah, bh, a, 0, 0, 0);
                a = __builtin_amdgcn_mfma_f32_16x16x32_bf16(ah, bl, a, 0, 0, 0);
                a = __builtin_amdgcn_mfma_f32_16x16x32_bf16(al, bh, a, 0, 0, 0);
                if (ot == 0) acc0 = a; else if (ot == 1) acc1 = a;
                else if (ot == 2) acc2 = a; else acc3 = a;
            }
        }
    }

    // ---- epilogue: pack into LDS transpose buffer, coalesced 16B stores ----
    __syncthreads();                  // staging reads done; safe to alias LB
    unsigned (*T)[68] = (unsigned(*)[68])LB;
    {
        u32x4 pv;
        pv[0] = packhl(acc0[0]); pv[1] = packhl(acc0[1]);
        pv[2] = packhl(acc0[2]); pv[3] = packhl(acc0[3]);
        *(u32x4*)&T[w * 16 + lc][0 * 16 + grp * 4] = pv;
        pv[0] = packhl(acc1[0]); pv[1] = packhl(acc1[1]);
        pv[2] = packhl(acc1[2]); pv[3] = packhl(acc1[3]);
        *(u32x4*)&T[w * 16 + lc][1 * 16 + grp * 4] = pv;
        pv[0] = packhl(acc2[0]); pv[1] = packhl(acc2[1]);
        pv[2] = packhl(acc2[2]); pv[3] = packhl(acc2[3]);
        *(u32x4*)&T[w * 16 + lc][2 * 16 + grp * 4] = pv;
        pv[0] = packhl(acc3[0]); pv[1] = packhl(acc3[1]);
        pv[2] = packhl(acc3[2]); pv[3] = packhl(acc3[3]);
        *(u32x4*)&T[w * 16 + lc][3 * 16 + grp * 4] = pv;
    }
    __syncthreads();

    if (mode == 1 || otg < 2) {
        // psi / q readback: [px][8 consecutive h] -> 16B hi + 16B lo stores
        ush* PH = (mode == 0) ? psiH : qH;
        ush* PL = (mode == 0) ? psiL : qL;
        #pragma unroll
        for (int it = 0; it < 2; ++it) {
            int idx = it * 256 + t;
            int pxl = idx >> 3, ch = idx & 7;
            u32x4 v0 = *(const u32x4*)&T[pxl][ch * 8];
            u32x4 v1 = *(const u32x4*)&T[pxl][ch * 8 + 4];
            ush8x hi, lo;
            #pragma unroll
            for (int i = 0; i < 4; ++i) {
                hi[i] = (ush)(v0[i] & 0xffffu); lo[i] = (ush)(v0[i] >> 16);
                hi[4 + i] = (ush)(v1[i] & 0xffffu); lo[4 + i] = (ush)(v1[i] >> 16);
            }
            int pix = pxBase + pxl;
            size_t base;
            if (mode == 0)
                base = ((size_t)(b * DC_ + d) * HW_ + pix) * HC_ + otg * 64 + ch * 8;
            else
                base = ((size_t)b * HW_ + pix) * HC_ + otg * 64 + ch * 8;
            *(ush8x*)&PH[base] = hi;
            *(ush8x*)&PL[base] = lo;
        }
    } else {
        // g readback: [o][8 consecutive px] -> 16B stores into unpadded gtmp
        #pragma unroll
        for (int it = 0; it < 2; ++it) {
            int idx = it * 256 + t;
            int ol = idx >> 3, pg = idx & 7;
            ush8x hv;
            #pragma unroll
            for (int i = 0; i < 8; ++i)
                hv[i] = (ush)(T[pg * 8 + i][ol] & 0xffffu);
            int og = (otg - 2) * 64 + ol;
            int pxg = pxBase + pg * 8;          // 8-px groups never straddle y
            int yy = pxg / W_, xx = pxg - yy * W_;
            *(ush8x*)&gtmp[(((size_t)(b * HC_ + og) * DC_ + d) * H_ + yy) * W_ + xx] = hv;
        }
    }
}

// ---------------------------------------------------------------------------
// 1b) pad: gtmp rows (48) -> gB rows (64) with +3 shift and edge replication.
__global__ __launch_bounds__(256) void pad2_kernel(
    const ush* __restrict__ gtmp, ush* __restrict__ gB)
{
    __shared__ ush R[32][48];
    int blk = blockIdx.x, t = threadIdx.x;
    int r = t >> 3, ch = t & 7;
    size_t row = (size_t)blk * 32 + r;
    if (ch < 6)
        *(ush8x*)&R[r][ch * 8] = *(const ush8x*)&gtmp[row * W_ + ch * 8];
    __syncthreads();
    ush8x o;
    #pragma unroll
    for (int i = 0; i < 8; ++i) {
        int x = ch * 8 + i - 3;
        x = min(max(x, 0), W_ - 1);
        o[i] = R[r][x];
    }
    *(ush8x*)&gB[row * GW + ch * 8] = o;
}

// ---------------------------------------------------------------------------
// 2) MFMA band-GEMM attention with compensated-bf16 scores (unchanged).
__global__ __launch_bounds__(512) void attn_mfma_kernel(
    const ush* __restrict__ qHp, const ush* __restrict__ qLp,
    const ush* __restrict__ psiHp, const ush* __restrict__ psiLp,
    const ush* __restrict__ g,
    ush* __restrict__ yH, ush* __restrict__ yL)
{
    __shared__ float S[147 * 17];

    int bid = blockIdx.x;
    int tile = (bid & 7) * 36 + (bid >> 3);   // XCD-contiguous pixel rows
    int b = tile / 144;
    int tr = tile - b * 144;
    int y0 = tr / 3;
    int x0 = (tr % 3) * 16;

    int t = threadIdx.x;
    int w = t >> 6;
    int l = t & 63;
    int lc = l & 15;
    int grp = l >> 4;
    int pixBase = b * HW_ + y0 * W_ + x0;

    const ush* qrowH = qHp + (size_t)(pixBase + lc) * HC_ + grp * 8;
    const ush* qrowL = qLp + (size_t)(pixBase + lc) * HC_ + grp * 8;
    bf16x8 qh[4], ql[4];
    #pragma unroll
    for (int ks = 0; ks < 4; ++ks) {
        qh[ks] = *(const bf16x8*)(qrowH + ks * 32);
        ql[ks] = *(const bf16x8*)(qrowL + ks * 32);
    }

    // ---- scores ----
    for (int idx = w; idx < 21; idx += 8) {
        int d = idx / 7, i = idx - 7 * d;
        int ry = min(max(y0 + i - 3, 0), H_ - 1);
        size_t rowOff = ((size_t)(b * DC_ + d) * HW_ + ry * W_) * HC_;
        const ush* psiRowH = psiHp + rowOff;
        const ush* psiRowL = psiLp + rowOff;
        #pragma unroll
        for (int f = 0; f < 2; ++f) {
            int c = f * 16 + lc;
            int px = min(max(x0 + c - 3, 0), W_ - 1);
            const ush* bpH = psiRowH + (size_t)px * HC_ + grp * 8;
            const ush* bpL = psiRowL + (size_t)px * HC_ + grp * 8;
            f32x4 acc = {0.f, 0.f, 0.f, 0.f};
            #pragma unroll
            for (int ks = 0; ks < 4; ++ks) {
                bf16x8 ph = *(const bf16x8*)(bpH + ks * 32);
                bf16x8 pl = *(const bf16x8*)(bpL + ks * 32);
                acc = __builtin_amdgcn_mfma_f32_16x16x32_bf16(qh[ks], ph, acc, 0, 0, 0);
                acc = __builtin_amdgcn_mfma_f32_16x16x32_bf16(qh[ks], pl, acc, 0, 0, 0);
                acc = __builtin_amdgcn_mfma_f32_16x16x32_bf16(ql[ks], ph, acc, 0, 0, 0);
            }
            #pragma unroll
            for (int r = 0; r < 4; ++r) {
                int p = grp * 4 + r;
                int j = c - p;
                if (j >= 0 && j < 7) S[(idx * 7 + j) * 17 + p] = acc[r];
            }
        }
    }
    __syncthreads();

    // ---- softmax ----
    #pragma unroll
    for (int pi = 0; pi < 2; ++pi) {
        int p = w * 2 + pi;
        float s0 = S[l * 17 + p];
        float s1 = S[(64 + l) * 17 + p];
        float s2 = (l + 128 < K_) ? S[(128 + l) * 17 + p] : -1e30f;
        float m = fmaxf(fmaxf(s0, s1), s2);
        #pragma unroll
        for (int off = 32; off; off >>= 1) m = fmaxf(m, __shfl_xor(m, off));
        float e0 = __expf(s0 - m), e1 = __expf(s1 - m), e2 = __expf(s2 - m);
        float sum = e0 + e1 + e2;
        #pragma unroll
        for (int off = 32; off; off >>= 1) sum += __shfl_xor(sum, off);
        float inv = 1.0f / sum;
        S[l * 17 + p] = e0 * inv;
        S[(64 + l) * 17 + p] = e1 * inv;
        if (l + 128 < K_) S[(128 + l) * 17 + p] = e2 * inv;
    }
    __syncthreads();

    // ---- PV ----
    int hB = w * 16 + lc;
    f32x4 acc = {0.f, 0.f, 0.f, 0.f};
    for (int idx = 0; idx < 21; ++idx) {
        int d = idx / 7, i = idx - 7 * d;
        int ry = min(max(y0 + i - 3, 0), H_ - 1);
        unsigned au[4];
        #pragma unroll
        for (int rr = 0; rr < 4; ++rr) {
            int k0 = grp * 8 + rr * 2;
            int j0 = k0 - lc, j1 = k0 + 1 - lc;
            float v0 = (j0 >= 0 && j0 < 7) ? S[(idx * 7 + j0) * 17 + lc] : 0.f;
            float v1 = (j1 >= 0 && j1 < 7) ? S[(idx * 7 + j1) * 17 + lc] : 0.f;
            au[rr] = (unsigned)f2bf(v0) | ((unsigned)f2bf(v1) << 16);
        }
        union { unsigned u[4]; bf16x8 v; } af;
        af.u[0] = au[0]; af.u[1] = au[1]; af.u[2] = au[2]; af.u[3] = au[3];
        const ush* gb = g
            + (((size_t)(b * HC_ + hB) * DC_ + d) * H_ + ry) * GW + x0 + grp * 8;
        bf16x8 bg = *(const bf16x8*)gb;
        acc = __builtin_amdgcn_mfma_f32_16x16x32_bf16(af.v, bg, acc, 0, 0, 0);
    }
    #pragma unroll
    for (int r = 0; r < 4; ++r) {
        int p = grp * 4 + r;
        size_t o = (size_t)(pixBase + p) * HC_ + hB;
        float v = acc[r];
        ush hh = f2bf(v);
        yH[o] = hh;
        yL[o] = f2bf(v - bf2f(hh));
    }
}

// ---------------------------------------------------------------------------
// 3) wy = W_w @ y via MFMA, compensated bf16, direct global loads (unchanged).
__global__ __launch_bounds__(512) void wy_mfma_kernel(
    const ush* __restrict__ WwH, const ush* __restrict__ WwL,
    const ush* __restrict__ yHp, const ush* __restrict__ yLp,
    float* __restrict__ wyO)
{
    int blk = blockIdx.x;              // 144
    int t = threadIdx.x;
    int l = t & 63, w = t >> 6;
    int lc = l & 15, grp = l >> 4;
    int pxg = blk * 32 + (w & 1) * 16 + lc;
    int b = pxg / HW_;
    int p = pxg - b * HW_;

    bf16x8 bH[4], bL[4];
    #pragma unroll
    for (int ks = 0; ks < 4; ++ks) {
        bH[ks] = *(const bf16x8*)&yHp[(size_t)pxg * HC_ + ks * 32 + grp * 8];
        bL[ks] = *(const bf16x8*)&yLp[(size_t)pxg * HC_ + ks * 32 + grp * 8];
    }

    int otBase = (w >> 1) * 4;
    #pragma unroll
    for (int oi = 0; oi < 4; ++oi) {
        int ot = otBase + oi;
        const ush* wrH = WwH + (size_t)(ot * 16 + lc) * HC_ + grp * 8;
        const ush* wrL = WwL + (size_t)(ot * 16 + lc) * HC_ + grp * 8;
        f32x4 acc = {0.f, 0.f, 0.f, 0.f};
        #pragma unroll
        for (int ks = 0; ks < 4; ++ks) {
            bf16x8 aH = *(const bf16x8*)(wrH + ks * 32);
            bf16x8 aL = *(const bf16x8*)(wrL + ks * 32);
            acc = __builtin_amdgcn_mfma_f32_16x16x32_bf16(aH, bH[ks], acc, 0, 0, 0);
            acc = __builtin_amdgcn_mfma_f32_16x16x32_bf16(aH, bL[ks], acc, 0, 0, 0);
            acc = __builtin_amdgcn_mfma_f32_16x16x32_bf16(aL, bH[ks], acc, 0, 0, 0);
        }
        int o0 = ot * 16 + grp * 4;
        #pragma unroll
        for (int r2 = 0; r2 < 4; ++r2)
            wyO[(size_t)(b * C_ + o0 + r2) * HW_ + p] = acc[r2];
    }
}

// ---------------------------------------------------------------------------
// 4) BN batch stats per channel -> folded scale/shift.  grid = 256
__global__ __launch_bounds__(256) void bn_stats_kernel(
    const float* __restrict__ wy, const float* __restrict__ gamma,
    const float* __restrict__ beta, float2* __restrict__ stats)
{
    int o = blockIdx.x;
    int tid = threadIdx.x;
    float s = 0.f, s2 = 0.f;
    for (int idx = tid; idx < NP_; idx += 256) {
        int b = idx / HW_;
        int p = idx - b * HW_;
        float v = wy[(size_t)(b * C_ + o) * HW_ + p];
        s += v;
        s2 = fmaf(v, v, s2);
    }
    #pragma unroll
    for (int off = 32; off; off >>= 1) {
        s  += __shfl_xor(s, off);
        s2 += __shfl_xor(s2, off);
    }
    __shared__ float ls[4], ls2[4];
    int wv = tid >> 6, lane = tid & 63;
    if (lane == 0) { ls[wv] = s; ls2[wv] = s2; }
    __syncthreads();
    if (tid == 0) {
        float S  = ls[0] + ls[1] + ls[2] + ls[3];
        float S2 = ls2[0] + ls2[1] + ls2[2] + ls2[3];
        float mean = S / (float)NP_;
        float var = fmaxf(S2 / (float)NP_ - mean * mean, 0.f);
        float rstd = rsqrtf(var + 1e-5f);
        float sc = gamma[o] * rstd;
        stats[o] = make_float2(sc, beta[o] - mean * sc);
    }
}

// ---------------------------------------------------------------------------
// 5) z = x + wy*scale + shift
__global__ __launch_bounds__(256) void final_kernel(
    const float* __restrict__ x, const float* __restrict__ wy,
    const float2* __restrict__ stats, float* __restrict__ out)
{
    int idx = blockIdx.x * 256 + threadIdx.x;
    int e0 = idx * 4;
    int c = (e0 / HW_) & (C_ - 1);
    float2 st = stats[c];
    float4 xv = *(const float4*)(x + e0);
    float4 wv = *(const float4*)(wy + e0);
    float4 o;
    o.x = fmaf(wv.x, st.x, xv.x + st.y);
    o.y = fmaf(wv.y, st.x, xv.y + st.y);
    o.z = fmaf(wv.z, st.x, xv.z + st.y);
    o.w = fmaf(wv.w, st.x, xv.w + st.y);
    *(float4*)(out + e0) = o;
}

extern "C" void kernel_launch(void* const* d_in, const int* in_sizes, int n_in,
                              void* d_out, int out_size, void* d_ws, size_t ws_size,
                              hipStream_t stream) {
    const float* x       = (const float*)d_in[0];
    const float* ctx     = (const float*)d_in[1];
    const float* theta_w = (const float*)d_in[2];
    const float* psi_w   = (const float*)d_in[3];
    const float* g_w     = (const float*)d_in[4];
    const float* W_w     = (const float*)d_in[5];
    // d_in[6] = W_b: unused, cancels exactly under training-mode BN
    const float* gamma   = (const float*)d_in[7];
    const float* beta    = (const float*)d_in[8];
    float* out = (float*)d_out;

    ush* ws = (ush*)d_ws;
    ush* qH    = ws;                     // 589824
    ush* qL    = qH + 589824;
    ush* psiH  = qL + 589824;            // 1769472
    ush* psiL  = psiH + 1769472;
    ush* gB    = psiL + 1769472;         // 2359296  [B,128,3,48,64] padded
    ush* gtmp  = gB + 2359296;           // 3538944  [B,128,3,48,48] unpadded
    ush* WpgH  = gtmp + 3538944;         // 65536
    ush* WpgL  = WpgH + 65536;
    ush* WqH   = WpgL + 65536;           // 32768
    ush* WqL   = WqH + 32768;
    ush* WwH   = WqL + 32768;            // 32768
    ush* WwL   = WwH + 32768;
    ush* ctxTH = WwL + 32768;            // 3538944
    ush* ctxTL = ctxTH + 3538944;
    ush* xTH   = ctxTL + 3538944;        // 1179648
    ush* xTL   = xTH + 1179648;
    float2* stats = (float2*)(xTL + 1179648);
    // aliases (stream-ordered single-call lifetimes, deterministic each call):
    float* wyB = (float*)ctxTH;          // 1179648 f32 <= ctxT region
    ush* yH = xTH;                       // y produced after proj consumed xT
    ush* yL = xTH + 589824;

    split_w_kernel<<<dim3(128), 256, 0, stream>>>(psi_w, g_w, theta_w, W_w,
                                                  WpgH, WpgL, WqH, WqL, WwH, WwL);
    xpose_kernel<<<dim3(1152), 256, 0, stream>>>(ctx, x, ctxTH, ctxTL, xTH, xTL);
    proj4_kernel<<<dim3(1008), 256, 0, stream>>>(WpgH, WpgL, WqH, WqL,
                                                 ctxTH, ctxTL, xTH, xTL,
                                                 psiH, psiL, gtmp, qH, qL);
    pad2_kernel<<<dim3(1152), 256, 0, stream>>>(gtmp, gB);
    attn_mfma_kernel<<<dim3(288), 512, 0, stream>>>(qH, qL, psiH, psiL, gB, yH, yL);
    wy_mfma_kernel<<<dim3(144), 512, 0, stream>>>(WwH, WwL, yH, yL, wyB);
    bn_stats_kernel<<<dim3(C_), 256, 0, stream>>>(wyB, gamma, beta, stats);
    final_kernel<<<dim3(B_ * C_ * HW_ / 4 / 256), 256, 0, stream>>>(x, wyB, stats, out);
}

// Round 11
// 78.954 us; speedup vs baseline: 1.5451x; 1.1135x over previous
//
#include <hip/hip_runtime.h>
#include <cmath>

#define B_   2
#define C_   256
#define HC_  128
#define DC_  3
#define H_   48
#define W_   48
#define HW_  (H_ * W_)      // 2304
#define NP_  (B_ * HW_)     // 4608
#define K_   (DC_ * 49)     // 147
#define GW   64             // padded g width (col = x+3, 16B-aligned rows)

typedef unsigned short ush;
typedef __attribute__((ext_vector_type(8))) short bf16x8;
typedef __attribute__((ext_vector_type(8))) unsigned short ush8x;
typedef __attribute__((ext_vector_type(4))) float f32x4;
typedef __attribute__((ext_vector_type(4))) unsigned u32x4;

__device__ inline ush f2bf(float f) {
    union { float f; unsigned u; } v; v.f = f;
    unsigned r = v.u + 0x7FFF + ((v.u >> 16) & 1);
    return (ush)(r >> 16);
}
__device__ inline float bf2f(ush h) {
    union { unsigned u; float f; } v; v.u = ((unsigned)h) << 16;
    return v.f;
}
__device__ inline unsigned packhl(float f) {
    ush h = f2bf(f);
    ush l = f2bf(f - bf2f(h));
    return (unsigned)h | ((unsigned)l << 16);
}
__device__ __forceinline__ void gload16(const void* g, void* l) {
    __builtin_amdgcn_global_load_lds(
        (const __attribute__((address_space(1))) unsigned*)g,
        (__attribute__((address_space(3))) unsigned*)l, 16, 0, 0);
}

// ---------------------------------------------------------------------------
// 0) prep: blocks 0..1151 = transpose+split ctx/x -> ctxT/xT hi/lo;
//          blocks 1152..1279 = weight hi/lo split.
__global__ __launch_bounds__(256) void prep_kernel(
    const float* __restrict__ ctx, const float* __restrict__ x,
    const float* __restrict__ psi_w, const float* __restrict__ g_w,
    const float* __restrict__ theta_w, const float* __restrict__ Ww,
    ush* __restrict__ ctxTH, ush* __restrict__ ctxTL,
    ush* __restrict__ xTH, ush* __restrict__ xTL,
    ush* __restrict__ WpgH, ush* __restrict__ WpgL,
    ush* __restrict__ WqH, ush* __restrict__ WqL,
    ush* __restrict__ WwH, ush* __restrict__ WwL)
{
    __shared__ float T[64][65];
    int id = blockIdx.x;
    if (id >= 1152) {
        // ---- weight split path (block-uniform early return) ----
        int idx = ((id - 1152) * 256 + threadIdx.x) * 4;
        float4 v;
        ush *dH, *dL;
        if (idx < 65536) {
            v = *(const float4*)(idx < 32768 ? psi_w + idx : g_w + (idx - 32768));
            dH = WpgH + idx; dL = WpgL + idx;
        } else if (idx < 98304) {
            v = *(const float4*)(theta_w + idx - 65536);
            dH = WqH + idx - 65536; dL = WqL + idx - 65536;
        } else {
            v = *(const float4*)(Ww + idx - 98304);
            dH = WwH + idx - 98304; dL = WwL + idx - 98304;
        }
        ushort4 h, l;
        h.x = f2bf(v.x); l.x = f2bf(v.x - bf2f(h.x));
        h.y = f2bf(v.y); l.y = f2bf(v.y - bf2f(h.y));
        h.z = f2bf(v.z); l.z = f2bf(v.z - bf2f(h.z));
        h.w = f2bf(v.w); l.w = f2bf(v.w - bf2f(h.w));
        *(ushort4*)dH = h; *(ushort4*)dL = l;
        return;
    }
    // ---- transpose path ----
    const float* src;
    ush *dH, *dL;
    size_t rowStride;
    if (id < 864) {
        int ct = id & 3, pt = (id >> 2) % 36, bd = id / 144;
        int b = bd / 3, d = bd % 3;
        int c0 = ct * 64, p0 = pt * 64;
        src = ctx + ((size_t)(b * 256 + c0) * 3 + d) * HW_ + p0;
        rowStride = 3 * HW_;
        size_t ob = ((size_t)(b * 3 + d) * HW_ + p0) * 256 + c0;
        dH = ctxTH + ob; dL = ctxTL + ob;
    } else {
        int id2 = id - 864;
        int ct = id2 & 3, pt = (id2 >> 2) % 36, b = id2 / 144;
        int c0 = ct * 64, p0 = pt * 64;
        src = x + (size_t)(b * 256 + c0) * HW_ + p0;
        rowStride = HW_;
        size_t ob = ((size_t)b * HW_ + p0) * 256 + c0;
        dH = xTH + ob; dL = xTL + ob;
    }
    int t = threadIdx.x;
    int cl = t >> 4, p4 = (t & 15) * 4;
    #pragma unroll
    for (int r = 0; r < 4; ++r) {
        int c = cl + r * 16;
        float4 v = *(const float4*)(src + (size_t)c * rowStride + p4);
        T[c][p4] = v.x; T[c][p4 + 1] = v.y; T[c][p4 + 2] = v.z; T[c][p4 + 3] = v.w;
    }
    __syncthreads();
    int pl = t >> 2, ch = t & 3;
    #pragma unroll
    for (int s = 0; s < 2; ++s) {
        int c8 = (ch + s * 4) * 8;
        ush8x vh, vl;
        #pragma unroll
        for (int i = 0; i < 8; ++i) {
            float f = T[c8 + i][pl];
            ush hh = f2bf(f);
            vh[i] = hh;
            vl[i] = f2bf(f - bf2f(hh));
        }
        *(ush8x*)(dH + (size_t)pl * 256 + c8) = vh;
        *(ush8x*)(dL + (size_t)pl * 256 + c8) = vl;
    }
}

// ---------------------------------------------------------------------------
// 1) proj4: m97-style MFMA GEMM with global_load_lds staging (unchanged).
__global__ __launch_bounds__(256) void proj4_kernel(
    const ush* __restrict__ WpgH, const ush* __restrict__ WpgL,
    const ush* __restrict__ WqH, const ush* __restrict__ WqL,
    const ush* __restrict__ ctxTH, const ush* __restrict__ ctxTL,
    const ush* __restrict__ xTH, const ush* __restrict__ xTL,
    ush* __restrict__ psiH, ush* __restrict__ psiL,
    ush* __restrict__ gtmp, ush* __restrict__ qH, ush* __restrict__ qL)
{
    __shared__ __align__(16) unsigned char LB[32768];  // A-H|A-L|B-H|B-L 8KB each

    int bid = blockIdx.x;
    int swz = (bid & 7) * 126 + (bid >> 3);   // 1008 = 8*126, XCD-contiguous
    int t = threadIdx.x, w = t >> 6, l = t & 63, lc = l & 15, grp = l >> 4;
    int mode, b, d, pxBase, otg;
    const ush *XH, *XL, *WH, *WL;
    if (swz < 864) {
        mode = 0; otg = swz & 3;               // 0,1: psi  2,3: g
        int rest = swz >> 2;                   // 0..215
        int pxt = rest % 36, bd = rest / 36;
        b = bd / 3; d = bd % 3;
        pxBase = pxt * 64;
        size_t xb = (size_t)(b * 3 + d) * HW_ * 256;
        XH = ctxTH + xb; XL = ctxTL + xb;
        WH = WpgH; WL = WpgL;
    } else {
        mode = 1;
        int id2 = swz - 864; otg = id2 & 1;
        int rest = id2 >> 1;                   // 0..71
        int pxt = rest % 36; b = rest / 36; d = 0;
        pxBase = pxt * 64;
        size_t xb = (size_t)b * HW_ * 256;
        XH = xTH + xb; XL = xTL + xb;
        WH = WqH; WL = WqL;
    }

    // staging role per wave: 0=A-H 1=A-L 2=B-H 3=B-L
    const ush* GSRC = (w == 0) ? WH : (w == 1) ? WL : (w == 2) ? XH : XL;
    int rowBase = (w < 2) ? (otg * 64) : pxBase;
    int r8 = l >> 3;                  // row within 8-row group
    int kg = (l & 7) ^ r8;            // fetched kgroup (slot = l&7, swizzle)
    unsigned char* ldsPlane = LB + w * 8192;

    f32x4 acc0 = {0,0,0,0}, acc1 = {0,0,0,0}, acc2 = {0,0,0,0}, acc3 = {0,0,0,0};

    for (int kst = 0; kst < 4; ++kst) {
        __syncthreads();              // previous tile fully consumed
        #pragma unroll
        for (int wl = 0; wl < 8; ++wl) {
            int row = rowBase + wl * 8 + r8;
            gload16(GSRC + (size_t)row * 256 + kst * 64 + kg * 8,
                    ldsPlane + wl * 1024);
        }
        __syncthreads();              // compiler drains vmcnt before barrier

        #pragma unroll
        for (int ksub = 0; ksub < 2; ++ksub) {
            int sw = ((ksub * 4 + grp) ^ (lc & 7)) << 4;
            int brow = w * 16 + lc;
            bf16x8 bh = *(const bf16x8*)(LB + 16384 + brow * 128 + sw);
            bf16x8 bl = *(const bf16x8*)(LB + 24576 + brow * 128 + sw);
            #pragma unroll
            for (int ot = 0; ot < 4; ++ot) {
                int arow = ot * 16 + lc;
                bf16x8 ah = *(const bf16x8*)(LB +        arow * 128 + sw);
                bf16x8 al = *(const bf16x8*)(LB + 8192 + arow * 128 + sw);
                f32x4 a = (ot == 0) ? acc0 : (ot == 1) ? acc1 : (ot == 2) ? acc2 : acc3;
                a = __builtin_amdgcn_mfma_f32_16x16x32_bf16(ah, bh, a, 0, 0, 0);
                a = __builtin_amdgcn_mfma_f32_16x16x32_bf16(ah, bl, a, 0, 0, 0);
                a = __builtin_amdgcn_mfma_f32_16x16x32_bf16(al, bh, a, 0, 0, 0);
                if (ot == 0) acc0 = a; else if (ot == 1) acc1 = a;
                else if (ot == 2) acc2 = a; else acc3 = a;
            }
        }
    }

    // ---- epilogue: pack into LDS transpose buffer, coalesced 16B stores ----
    __syncthreads();                  // staging reads done; safe to alias LB
    unsigned (*T)[68] = (unsigned(*)[68])LB;
    {
        u32x4 pv;
        pv[0] = packhl(acc0[0]); pv[1] = packhl(acc0[1]);
        pv[2] = packhl(acc0[2]); pv[3] = packhl(acc0[3]);
        *(u32x4*)&T[w * 16 + lc][0 * 16 + grp * 4] = pv;
        pv[0] = packhl(acc1[0]); pv[1] = packhl(acc1[1]);
        pv[2] = packhl(acc1[2]); pv[3] = packhl(acc1[3]);
        *(u32x4*)&T[w * 16 + lc][1 * 16 + grp * 4] = pv;
        pv[0] = packhl(acc2[0]); pv[1] = packhl(acc2[1]);
        pv[2] = packhl(acc2[2]); pv[3] = packhl(acc2[3]);
        *(u32x4*)&T[w * 16 + lc][2 * 16 + grp * 4] = pv;
        pv[0] = packhl(acc3[0]); pv[1] = packhl(acc3[1]);
        pv[2] = packhl(acc3[2]); pv[3] = packhl(acc3[3]);
        *(u32x4*)&T[w * 16 + lc][3 * 16 + grp * 4] = pv;
    }
    __syncthreads();

    if (mode == 1 || otg < 2) {
        // psi / q readback: [px][8 consecutive h] -> 16B hi + 16B lo stores
        ush* PH = (mode == 0) ? psiH : qH;
        ush* PL = (mode == 0) ? psiL : qL;
        #pragma unroll
        for (int it = 0; it < 2; ++it) {
            int idx = it * 256 + t;
            int pxl = idx >> 3, ch = idx & 7;
            u32x4 v0 = *(const u32x4*)&T[pxl][ch * 8];
            u32x4 v1 = *(const u32x4*)&T[pxl][ch * 8 + 4];
            ush8x hi, lo;
            #pragma unroll
            for (int i = 0; i < 4; ++i) {
                hi[i] = (ush)(v0[i] & 0xffffu); lo[i] = (ush)(v0[i] >> 16);
                hi[4 + i] = (ush)(v1[i] & 0xffffu); lo[4 + i] = (ush)(v1[i] >> 16);
            }
            int pix = pxBase + pxl;
            size_t base;
            if (mode == 0)
                base = ((size_t)(b * DC_ + d) * HW_ + pix) * HC_ + otg * 64 + ch * 8;
            else
                base = ((size_t)b * HW_ + pix) * HC_ + otg * 64 + ch * 8;
            *(ush8x*)&PH[base] = hi;
            *(ush8x*)&PL[base] = lo;
        }
    } else {
        // g readback: [o][8 consecutive px] -> 16B stores into unpadded gtmp
        #pragma unroll
        for (int it = 0; it < 2; ++it) {
            int idx = it * 256 + t;
            int ol = idx >> 3, pg = idx & 7;
            ush8x hv;
            #pragma unroll
            for (int i = 0; i < 8; ++i)
                hv[i] = (ush)(T[pg * 8 + i][ol] & 0xffffu);
            int og = (otg - 2) * 64 + ol;
            int pxg = pxBase + pg * 8;          // 8-px groups never straddle y
            int yy = pxg / W_, xx = pxg - yy * W_;
            *(ush8x*)&gtmp[(((size_t)(b * HC_ + og) * DC_ + d) * H_ + yy) * W_ + xx] = hv;
        }
    }
}

// ---------------------------------------------------------------------------
// 1b) pad: gtmp rows (48) -> gB rows (64) with +3 shift and edge replication.
__global__ __launch_bounds__(256) void pad2_kernel(
    const ush* __restrict__ gtmp, ush* __restrict__ gB)
{
    __shared__ ush R[32][48];
    int blk = blockIdx.x, t = threadIdx.x;
    int r = t >> 3, ch = t & 7;
    size_t row = (size_t)blk * 32 + r;
    if (ch < 6)
        *(ush8x*)&R[r][ch * 8] = *(const ush8x*)&gtmp[row * W_ + ch * 8];
    __syncthreads();
    ush8x o;
    #pragma unroll
    for (int i = 0; i < 8; ++i) {
        int x = ch * 8 + i - 3;
        x = min(max(x, 0), W_ - 1);
        o[i] = R[r][x];
    }
    *(ush8x*)&gB[row * GW + ch * 8] = o;
}

// ---------------------------------------------------------------------------
// 2) FUSED attention + wy. Scores/softmax/PV as before; PV result goes to
//    LDS Y planes (padded [16][136]), then wy = Ww @ y in-kernel (24 MFMAs
//    per wave, Ww from L2), writing wy f32 directly. No y global round-trip.
__global__ __launch_bounds__(512, 4) void attn_wy_kernel(
    const ush* __restrict__ qHp, const ush* __restrict__ qLp,
    const ush* __restrict__ psiHp, const ush* __restrict__ psiLp,
    const ush* __restrict__ g,
    const ush* __restrict__ WwH, const ush* __restrict__ WwL,
    float* __restrict__ wyO)
{
    __shared__ float S[147 * 17];
    __shared__ ush YH[16][136], YL[16][136];

    int bid = blockIdx.x;
    int tile = (bid & 7) * 36 + (bid >> 3);   // XCD-contiguous pixel rows
    int b = tile / 144;
    int tr = tile - b * 144;
    int y0 = tr / 3;
    int x0 = (tr % 3) * 16;

    int t = threadIdx.x;
    int w = t >> 6;
    int l = t & 63;
    int lc = l & 15;
    int grp = l >> 4;
    int pImg = y0 * W_ + x0;
    int pixBase = b * HW_ + pImg;

    const ush* qrowH = qHp + (size_t)(pixBase + lc) * HC_ + grp * 8;
    const ush* qrowL = qLp + (size_t)(pixBase + lc) * HC_ + grp * 8;
    bf16x8 qh[4], ql[4];
    #pragma unroll
    for (int ks = 0; ks < 4; ++ks) {
        qh[ks] = *(const bf16x8*)(qrowH + ks * 32);
        ql[ks] = *(const bf16x8*)(qrowL + ks * 32);
    }

    // ---- scores ----
    for (int idx = w; idx < 21; idx += 8) {
        int d = idx / 7, i = idx - 7 * d;
        int ry = min(max(y0 + i - 3, 0), H_ - 1);
        size_t rowOff = ((size_t)(b * DC_ + d) * HW_ + ry * W_) * HC_;
        const ush* psiRowH = psiHp + rowOff;
        const ush* psiRowL = psiLp + rowOff;
        #pragma unroll
        for (int f = 0; f < 2; ++f) {
            int c = f * 16 + lc;
            int px = min(max(x0 + c - 3, 0), W_ - 1);
            const ush* bpH = psiRowH + (size_t)px * HC_ + grp * 8;
            const ush* bpL = psiRowL + (size_t)px * HC_ + grp * 8;
            f32x4 acc = {0.f, 0.f, 0.f, 0.f};
            #pragma unroll
            for (int ks = 0; ks < 4; ++ks) {
                bf16x8 ph = *(const bf16x8*)(bpH + ks * 32);
                bf16x8 pl = *(const bf16x8*)(bpL + ks * 32);
                acc = __builtin_amdgcn_mfma_f32_16x16x32_bf16(qh[ks], ph, acc, 0, 0, 0);
                acc = __builtin_amdgcn_mfma_f32_16x16x32_bf16(qh[ks], pl, acc, 0, 0, 0);
                acc = __builtin_amdgcn_mfma_f32_16x16x32_bf16(ql[ks], ph, acc, 0, 0, 0);
            }
            #pragma unroll
            for (int r = 0; r < 4; ++r) {
                int p = grp * 4 + r;
                int j = c - p;
                if (j >= 0 && j < 7) S[(idx * 7 + j) * 17 + p] = acc[r];
            }
        }
    }
    __syncthreads();

    // ---- softmax ----
    #pragma unroll
    for (int pi = 0; pi < 2; ++pi) {
        int p = w * 2 + pi;
        float s0 = S[l * 17 + p];
        float s1 = S[(64 + l) * 17 + p];
        float s2 = (l + 128 < K_) ? S[(128 + l) * 17 + p] : -1e30f;
        float m = fmaxf(fmaxf(s0, s1), s2);
        #pragma unroll
        for (int off = 32; off; off >>= 1) m = fmaxf(m, __shfl_xor(m, off));
        float e0 = __expf(s0 - m), e1 = __expf(s1 - m), e2 = __expf(s2 - m);
        float sum = e0 + e1 + e2;
        #pragma unroll
        for (int off = 32; off; off >>= 1) sum += __shfl_xor(sum, off);
        float inv = 1.0f / sum;
        S[l * 17 + p] = e0 * inv;
        S[(64 + l) * 17 + p] = e1 * inv;
        if (l + 128 < K_) S[(128 + l) * 17 + p] = e2 * inv;
    }
    __syncthreads();

    // ---- PV ----
    int hB = w * 16 + lc;
    f32x4 acc = {0.f, 0.f, 0.f, 0.f};
    for (int idx = 0; idx < 21; ++idx) {
        int d = idx / 7, i = idx - 7 * d;
        int ry = min(max(y0 + i - 3, 0), H_ - 1);
        unsigned au[4];
        #pragma unroll
        for (int rr = 0; rr < 4; ++rr) {
            int k0 = grp * 8 + rr * 2;
            int j0 = k0 - lc, j1 = k0 + 1 - lc;
            float v0 = (j0 >= 0 && j0 < 7) ? S[(idx * 7 + j0) * 17 + lc] : 0.f;
            float v1 = (j1 >= 0 && j1 < 7) ? S[(idx * 7 + j1) * 17 + lc] : 0.f;
            au[rr] = (unsigned)f2bf(v0) | ((unsigned)f2bf(v1) << 16);
        }
        union { unsigned u[4]; bf16x8 v; } af;
        af.u[0] = au[0]; af.u[1] = au[1]; af.u[2] = au[2]; af.u[3] = au[3];
        const ush* gb = g
            + (((size_t)(b * HC_ + hB) * DC_ + d) * H_ + ry) * GW + x0 + grp * 8;
        bf16x8 bg = *(const bf16x8*)gb;
        acc = __builtin_amdgcn_mfma_f32_16x16x32_bf16(af.v, bg, acc, 0, 0, 0);
    }
    // PV result -> LDS Y planes (y[p][h] hi/lo, padded stride 136)
    #pragma unroll
    for (int r = 0; r < 4; ++r) {
        int p = grp * 4 + r;
        float v = acc[r];
        ush hh = f2bf(v);
        YH[p][hB] = hh;
        YL[p][hB] = f2bf(v - bf2f(hh));
    }
    __syncthreads();

    // ---- wy: wave w computes out-tiles 2w, 2w+1 (outs 32w..32w+31) ----
    #pragma unroll
    for (int oi = 0; oi < 2; ++oi) {
        int ot = w * 2 + oi;
        const ush* wrH = WwH + (size_t)(ot * 16 + lc) * HC_ + grp * 8;
        const ush* wrL = WwL + (size_t)(ot * 16 + lc) * HC_ + grp * 8;
        f32x4 a2 = {0.f, 0.f, 0.f, 0.f};
        #pragma unroll
        for (int ks = 0; ks < 4; ++ks) {
            bf16x8 bh = *(const bf16x8*)&YH[lc][ks * 32 + grp * 8];
            bf16x8 bl = *(const bf16x8*)&YL[lc][ks * 32 + grp * 8];
            bf16x8 aH = *(const bf16x8*)(wrH + ks * 32);
            bf16x8 aL = *(const bf16x8*)(wrL + ks * 32);
            a2 = __builtin_amdgcn_mfma_f32_16x16x32_bf16(aH, bh, a2, 0, 0, 0);
            a2 = __builtin_amdgcn_mfma_f32_16x16x32_bf16(aH, bl, a2, 0, 0, 0);
            a2 = __builtin_amdgcn_mfma_f32_16x16x32_bf16(aL, bh, a2, 0, 0, 0);
        }
        int o0 = ot * 16 + grp * 4;
        #pragma unroll
        for (int r2 = 0; r2 < 4; ++r2)
            wyO[(size_t)(b * C_ + o0 + r2) * HW_ + pImg + lc] = a2[r2];
    }
}

// ---------------------------------------------------------------------------
// 3) BN batch stats per channel -> folded scale/shift.  grid = 256
__global__ __launch_bounds__(256) void bn_stats_kernel(
    const float* __restrict__ wy, const float* __restrict__ gamma,
    const float* __restrict__ beta, float2* __restrict__ stats)
{
    int o = blockIdx.x;
    int tid = threadIdx.x;
    float s = 0.f, s2 = 0.f;
    for (int idx = tid; idx < NP_; idx += 256) {
        int b = idx / HW_;
        int p = idx - b * HW_;
        float v = wy[(size_t)(b * C_ + o) * HW_ + p];
        s += v;
        s2 = fmaf(v, v, s2);
    }
    #pragma unroll
    for (int off = 32; off; off >>= 1) {
        s  += __shfl_xor(s, off);
        s2 += __shfl_xor(s2, off);
    }
    __shared__ float ls[4], ls2[4];
    int wv = tid >> 6, lane = tid & 63;
    if (lane == 0) { ls[wv] = s; ls2[wv] = s2; }
    __syncthreads();
    if (tid == 0) {
        float S  = ls[0] + ls[1] + ls[2] + ls[3];
        float S2 = ls2[0] + ls2[1] + ls2[2] + ls2[3];
        float mean = S / (float)NP_;
        float var = fmaxf(S2 / (float)NP_ - mean * mean, 0.f);
        float rstd = rsqrtf(var + 1e-5f);
        float sc = gamma[o] * rstd;
        stats[o] = make_float2(sc, beta[o] - mean * sc);
    }
}

// ---------------------------------------------------------------------------
// 4) z = x + wy*scale + shift
__global__ __launch_bounds__(256) void final_kernel(
    const float* __restrict__ x, const float* __restrict__ wy,
    const float2* __restrict__ stats, float* __restrict__ out)
{
    int idx = blockIdx.x * 256 + threadIdx.x;
    int e0 = idx * 4;
    int c = (e0 / HW_) & (C_ - 1);
    float2 st = stats[c];
    float4 xv = *(const float4*)(x + e0);
    float4 wv = *(const float4*)(wy + e0);
    float4 o;
    o.x = fmaf(wv.x, st.x, xv.x + st.y);
    o.y = fmaf(wv.y, st.x, xv.y + st.y);
    o.z = fmaf(wv.z, st.x, xv.z + st.y);
    o.w = fmaf(wv.w, st.x, xv.w + st.y);
    *(float4*)(out + e0) = o;
}

extern "C" void kernel_launch(void* const* d_in, const int* in_sizes, int n_in,
                              void* d_out, int out_size, void* d_ws, size_t ws_size,
                              hipStream_t stream) {
    const float* x       = (const float*)d_in[0];
    const float* ctx     = (const float*)d_in[1];
    const float* theta_w = (const float*)d_in[2];
    const float* psi_w   = (const float*)d_in[3];
    const float* g_w     = (const float*)d_in[4];
    const float* W_w     = (const float*)d_in[5];
    // d_in[6] = W_b: unused, cancels exactly under training-mode BN
    const float* gamma   = (const float*)d_in[7];
    const float* beta    = (const float*)d_in[8];
    float* out = (float*)d_out;

    ush* ws = (ush*)d_ws;
    ush* qH    = ws;                     // 589824
    ush* qL    = qH + 589824;
    ush* psiH  = qL + 589824;            // 1769472
    ush* psiL  = psiH + 1769472;
    ush* gB    = psiL + 1769472;         // 2359296  [B,128,3,48,64] padded
    ush* gtmp  = gB + 2359296;           // 3538944  [B,128,3,48,48] unpadded
    ush* WpgH  = gtmp + 3538944;         // 65536
    ush* WpgL  = WpgH + 65536;
    ush* WqH   = WpgL + 65536;           // 32768
    ush* WqL   = WqH + 32768;
    ush* WwH   = WqL + 32768;            // 32768
    ush* WwL   = WwH + 32768;
    ush* ctxTH = WwL + 32768;            // 3538944
    ush* ctxTL = ctxTH + 3538944;
    ush* xTH   = ctxTL + 3538944;        // 1179648
    ush* xTL   = xTH + 1179648;
    float2* stats = (float2*)(xTL + 1179648);
    // alias (stream-ordered single-call lifetime, deterministic each call):
    float* wyB = (float*)ctxTH;          // 1179648 f32 <= ctxT region (proj done)

    prep_kernel<<<dim3(1280), 256, 0, stream>>>(ctx, x, psi_w, g_w, theta_w, W_w,
                                                ctxTH, ctxTL, xTH, xTL,
                                                WpgH, WpgL, WqH, WqL, WwH, WwL);
    proj4_kernel<<<dim3(1008), 256, 0, stream>>>(WpgH, WpgL, WqH, WqL,
                                                 ctxTH, ctxTL, xTH, xTL,
                                                 psiH, psiL, gtmp, qH, qL);
    pad2_kernel<<<dim3(1152), 256, 0, stream>>>(gtmp, gB);
    attn_wy_kernel<<<dim3(288), 512, 0, stream>>>(qH, qL, psiH, psiL, gB,
                                                  WwH, WwL, wyB);
    bn_stats_kernel<<<dim3(C_), 256, 0, stream>>>(wyB, gamma, beta, stats);
    final_kernel<<<dim3(B_ * C_ * HW_ / 4 / 256), 256, 0, stream>>>(x, wyB, stats, out);
}

// Round 12
// 78.806 us; speedup vs baseline: 1.5480x; 1.0019x over previous
//
#include <hip/hip_runtime.h>
#include <cmath>

#define B_   2
#define C_   256
#define HC_  128
#define DC_  3
#define H_   48
#define W_   48
#define HW_  (H_ * W_)      // 2304
#define NP_  (B_ * HW_)     // 4608
#define K_   (DC_ * 49)     // 147
#define GW   64             // padded g width (col = x+3, 16B-aligned rows)
#define SST  19             // S stride (words): PV read coeff -18*lc -> distinct banks
#define YST  152            // Y stride (ush): 304B rows, 16B-aligned, ~free reads

typedef unsigned short ush;
typedef __attribute__((ext_vector_type(8))) short bf16x8;
typedef __attribute__((ext_vector_type(8))) unsigned short ush8x;
typedef __attribute__((ext_vector_type(4))) float f32x4;
typedef __attribute__((ext_vector_type(4))) unsigned u32x4;

__device__ inline ush f2bf(float f) {
    union { float f; unsigned u; } v; v.f = f;
    unsigned r = v.u + 0x7FFF + ((v.u >> 16) & 1);
    return (ush)(r >> 16);
}
__device__ inline float bf2f(ush h) {
    union { unsigned u; float f; } v; v.u = ((unsigned)h) << 16;
    return v.f;
}
__device__ inline unsigned packhl(float f) {
    ush h = f2bf(f);
    ush l = f2bf(f - bf2f(h));
    return (unsigned)h | ((unsigned)l << 16);
}
__device__ __forceinline__ void gload16(const void* g, void* l) {
    __builtin_amdgcn_global_load_lds(
        (const __attribute__((address_space(1))) unsigned*)g,
        (__attribute__((address_space(3))) unsigned*)l, 16, 0, 0);
}

// ---------------------------------------------------------------------------
// 0) prep: blocks 0..1151 = transpose+split ctx/x -> ctxT/xT hi/lo;
//          blocks 1152..1279 = weight hi/lo split.
__global__ __launch_bounds__(256) void prep_kernel(
    const float* __restrict__ ctx, const float* __restrict__ x,
    const float* __restrict__ psi_w, const float* __restrict__ g_w,
    const float* __restrict__ theta_w, const float* __restrict__ Ww,
    ush* __restrict__ ctxTH, ush* __restrict__ ctxTL,
    ush* __restrict__ xTH, ush* __restrict__ xTL,
    ush* __restrict__ WpgH, ush* __restrict__ WpgL,
    ush* __restrict__ WqH, ush* __restrict__ WqL,
    ush* __restrict__ WwH, ush* __restrict__ WwL)
{
    __shared__ float T[64][65];
    int id = blockIdx.x;
    if (id >= 1152) {
        int idx = ((id - 1152) * 256 + threadIdx.x) * 4;
        float4 v;
        ush *dH, *dL;
        if (idx < 65536) {
            v = *(const float4*)(idx < 32768 ? psi_w + idx : g_w + (idx - 32768));
            dH = WpgH + idx; dL = WpgL + idx;
        } else if (idx < 98304) {
            v = *(const float4*)(theta_w + idx - 65536);
            dH = WqH + idx - 65536; dL = WqL + idx - 65536;
        } else {
            v = *(const float4*)(Ww + idx - 98304);
            dH = WwH + idx - 98304; dL = WwL + idx - 98304;
        }
        ushort4 h, l;
        h.x = f2bf(v.x); l.x = f2bf(v.x - bf2f(h.x));
        h.y = f2bf(v.y); l.y = f2bf(v.y - bf2f(h.y));
        h.z = f2bf(v.z); l.z = f2bf(v.z - bf2f(h.z));
        h.w = f2bf(v.w); l.w = f2bf(v.w - bf2f(h.w));
        *(ushort4*)dH = h; *(ushort4*)dL = l;
        return;
    }
    const float* src;
    ush *dH, *dL;
    size_t rowStride;
    if (id < 864) {
        int ct = id & 3, pt = (id >> 2) % 36, bd = id / 144;
        int b = bd / 3, d = bd % 3;
        int c0 = ct * 64, p0 = pt * 64;
        src = ctx + ((size_t)(b * 256 + c0) * 3 + d) * HW_ + p0;
        rowStride = 3 * HW_;
        size_t ob = ((size_t)(b * 3 + d) * HW_ + p0) * 256 + c0;
        dH = ctxTH + ob; dL = ctxTL + ob;
    } else {
        int id2 = id - 864;
        int ct = id2 & 3, pt = (id2 >> 2) % 36, b = id2 / 144;
        int c0 = ct * 64, p0 = pt * 64;
        src = x + (size_t)(b * 256 + c0) * HW_ + p0;
        rowStride = HW_;
        size_t ob = ((size_t)b * HW_ + p0) * 256 + c0;
        dH = xTH + ob; dL = xTL + ob;
    }
    int t = threadIdx.x;
    int cl = t >> 4, p4 = (t & 15) * 4;
    #pragma unroll
    for (int r = 0; r < 4; ++r) {
        int c = cl + r * 16;
        float4 v = *(const float4*)(src + (size_t)c * rowStride + p4);
        T[c][p4] = v.x; T[c][p4 + 1] = v.y; T[c][p4 + 2] = v.z; T[c][p4 + 3] = v.w;
    }
    __syncthreads();
    int pl = t >> 2, ch = t & 3;
    #pragma unroll
    for (int s = 0; s < 2; ++s) {
        int c8 = (ch + s * 4) * 8;
        ush8x vh, vl;
        #pragma unroll
        for (int i = 0; i < 8; ++i) {
            float f = T[c8 + i][pl];
            ush hh = f2bf(f);
            vh[i] = hh;
            vl[i] = f2bf(f - bf2f(hh));
        }
        *(ush8x*)(dH + (size_t)pl * 256 + c8) = vh;
        *(ush8x*)(dL + (size_t)pl * 256 + c8) = vl;
    }
}

// ---------------------------------------------------------------------------
// 1) proj4: m97-style MFMA GEMM with global_load_lds staging (unchanged).
__global__ __launch_bounds__(256) void proj4_kernel(
    const ush* __restrict__ WpgH, const ush* __restrict__ WpgL,
    const ush* __restrict__ WqH, const ush* __restrict__ WqL,
    const ush* __restrict__ ctxTH, const ush* __restrict__ ctxTL,
    const ush* __restrict__ xTH, const ush* __restrict__ xTL,
    ush* __restrict__ psiH, ush* __restrict__ psiL,
    ush* __restrict__ gtmp, ush* __restrict__ qH, ush* __restrict__ qL)
{
    __shared__ __align__(16) unsigned char LB[32768];  // A-H|A-L|B-H|B-L 8KB each

    int bid = blockIdx.x;
    int swz = (bid & 7) * 126 + (bid >> 3);   // 1008 = 8*126, XCD-contiguous
    int t = threadIdx.x, w = t >> 6, l = t & 63, lc = l & 15, grp = l >> 4;
    int mode, b, d, pxBase, otg;
    const ush *XH, *XL, *WH, *WL;
    if (swz < 864) {
        mode = 0; otg = swz & 3;               // 0,1: psi  2,3: g
        int rest = swz >> 2;                   // 0..215
        int pxt = rest % 36, bd = rest / 36;
        b = bd / 3; d = bd % 3;
        pxBase = pxt * 64;
        size_t xb = (size_t)(b * 3 + d) * HW_ * 256;
        XH = ctxTH + xb; XL = ctxTL + xb;
        WH = WpgH; WL = WpgL;
    } else {
        mode = 1;
        int id2 = swz - 864; otg = id2 & 1;
        int rest = id2 >> 1;                   // 0..71
        int pxt = rest % 36; b = rest / 36; d = 0;
        pxBase = pxt * 64;
        size_t xb = (size_t)b * HW_ * 256;
        XH = xTH + xb; XL = xTL + xb;
        WH = WqH; WL = WqL;
    }

    const ush* GSRC = (w == 0) ? WH : (w == 1) ? WL : (w == 2) ? XH : XL;
    int rowBase = (w < 2) ? (otg * 64) : pxBase;
    int r8 = l >> 3;
    int kg = (l & 7) ^ r8;
    unsigned char* ldsPlane = LB + w * 8192;

    f32x4 acc0 = {0,0,0,0}, acc1 = {0,0,0,0}, acc2 = {0,0,0,0}, acc3 = {0,0,0,0};

    for (int kst = 0; kst < 4; ++kst) {
        __syncthreads();
        #pragma unroll
        for (int wl = 0; wl < 8; ++wl) {
            int row = rowBase + wl * 8 + r8;
            gload16(GSRC + (size_t)row * 256 + kst * 64 + kg * 8,
                    ldsPlane + wl * 1024);
        }
        __syncthreads();

        #pragma unroll
        for (int ksub = 0; ksub < 2; ++ksub) {
            int sw = ((ksub * 4 + grp) ^ (lc & 7)) << 4;
            int brow = w * 16 + lc;
            bf16x8 bh = *(const bf16x8*)(LB + 16384 + brow * 128 + sw);
            bf16x8 bl = *(const bf16x8*)(LB + 24576 + brow * 128 + sw);
            #pragma unroll
            for (int ot = 0; ot < 4; ++ot) {
                int arow = ot * 16 + lc;
                bf16x8 ah = *(const bf16x8*)(LB +        arow * 128 + sw);
                bf16x8 al = *(const bf16x8*)(LB + 8192 + arow * 128 + sw);
                f32x4 a = (ot == 0) ? acc0 : (ot == 1) ? acc1 : (ot == 2) ? acc2 : acc3;
                a = __builtin_amdgcn_mfma_f32_16x16x32_bf16(ah, bh, a, 0, 0, 0);
                a = __builtin_amdgcn_mfma_f32_16x16x32_bf16(ah, bl, a, 0, 0, 0);
                a = __builtin_amdgcn_mfma_f32_16x16x32_bf16(al, bh, a, 0, 0, 0);
                if (ot == 0) acc0 = a; else if (ot == 1) acc1 = a;
                else if (ot == 2) acc2 = a; else acc3 = a;
            }
        }
    }

    __syncthreads();
    unsigned (*T)[68] = (unsigned(*)[68])LB;
    {
        u32x4 pv;
        pv[0] = packhl(acc0[0]); pv[1] = packhl(acc0[1]);
        pv[2] = packhl(acc0[2]); pv[3] = packhl(acc0[3]);
        *(u32x4*)&T[w * 16 + lc][0 * 16 + grp * 4] = pv;
        pv[0] = packhl(acc1[0]); pv[1] = packhl(acc1[1]);
        pv[2] = packhl(acc1[2]); pv[3] = packhl(acc1[3]);
        *(u32x4*)&T[w * 16 + lc][1 * 16 + grp * 4] = pv;
        pv[0] = packhl(acc2[0]); pv[1] = packhl(acc2[1]);
        pv[2] = packhl(acc2[2]); pv[3] = packhl(acc2[3]);
        *(u32x4*)&T[w * 16 + lc][2 * 16 + grp * 4] = pv;
        pv[0] = packhl(acc3[0]); pv[1] = packhl(acc3[1]);
        pv[2] = packhl(acc3[2]); pv[3] = packhl(acc3[3]);
        *(u32x4*)&T[w * 16 + lc][3 * 16 + grp * 4] = pv;
    }
    __syncthreads();

    if (mode == 1 || otg < 2) {
        ush* PH = (mode == 0) ? psiH : qH;
        ush* PL = (mode == 0) ? psiL : qL;
        #pragma unroll
        for (int it = 0; it < 2; ++it) {
            int idx = it * 256 + t;
            int pxl = idx >> 3, ch = idx & 7;
            u32x4 v0 = *(const u32x4*)&T[pxl][ch * 8];
            u32x4 v1 = *(const u32x4*)&T[pxl][ch * 8 + 4];
            ush8x hi, lo;
            #pragma unroll
            for (int i = 0; i < 4; ++i) {
                hi[i] = (ush)(v0[i] & 0xffffu); lo[i] = (ush)(v0[i] >> 16);
                hi[4 + i] = (ush)(v1[i] & 0xffffu); lo[4 + i] = (ush)(v1[i] >> 16);
            }
            int pix = pxBase + pxl;
            size_t base;
            if (mode == 0)
                base = ((size_t)(b * DC_ + d) * HW_ + pix) * HC_ + otg * 64 + ch * 8;
            else
                base = ((size_t)b * HW_ + pix) * HC_ + otg * 64 + ch * 8;
            *(ush8x*)&PH[base] = hi;
            *(ush8x*)&PL[base] = lo;
        }
    } else {
        #pragma unroll
        for (int it = 0; it < 2; ++it) {
            int idx = it * 256 + t;
            int ol = idx >> 3, pg = idx & 7;
            ush8x hv;
            #pragma unroll
            for (int i = 0; i < 8; ++i)
                hv[i] = (ush)(T[pg * 8 + i][ol] & 0xffffu);
            int og = (otg - 2) * 64 + ol;
            int pxg = pxBase + pg * 8;
            int yy = pxg / W_, xx = pxg - yy * W_;
            *(ush8x*)&gtmp[(((size_t)(b * HC_ + og) * DC_ + d) * H_ + yy) * W_ + xx] = hv;
        }
    }
}

// ---------------------------------------------------------------------------
// 1b) pad: gtmp rows (48) -> gB rows (64) with +3 shift and edge replication.
__global__ __launch_bounds__(256) void pad2_kernel(
    const ush* __restrict__ gtmp, ush* __restrict__ gB)
{
    __shared__ ush R[32][48];
    int blk = blockIdx.x, t = threadIdx.x;
    int r = t >> 3, ch = t & 7;
    size_t row = (size_t)blk * 32 + r;
    if (ch < 6)
        *(ush8x*)&R[r][ch * 8] = *(const ush8x*)&gtmp[row * W_ + ch * 8];
    __syncthreads();
    ush8x o;
    #pragma unroll
    for (int i = 0; i < 8; ++i) {
        int x = ch * 8 + i - 3;
        x = min(max(x, 0), W_ - 1);
        o[i] = R[r][x];
    }
    *(ush8x*)&gB[row * GW + ch * 8] = o;
}

// ---------------------------------------------------------------------------
// 2) FUSED attention + wy. S stride 19 (conflict-free PV reads), Y stride 152,
//    launch_bounds(512,2) -> 128 VGPR for load hoisting.
__global__ __launch_bounds__(512, 2) void attn_wy_kernel(
    const ush* __restrict__ qHp, const ush* __restrict__ qLp,
    const ush* __restrict__ psiHp, const ush* __restrict__ psiLp,
    const ush* __restrict__ g,
    const ush* __restrict__ WwH, const ush* __restrict__ WwL,
    float* __restrict__ wyO)
{
    __shared__ float S[147 * SST];
    __shared__ ush YH[16][YST], YL[16][YST];

    int bid = blockIdx.x;
    int tile = (bid & 7) * 36 + (bid >> 3);   // XCD-contiguous pixel rows
    int b = tile / 144;
    int tr = tile - b * 144;
    int y0 = tr / 3;
    int x0 = (tr % 3) * 16;

    int t = threadIdx.x;
    int w = t >> 6;
    int l = t & 63;
    int lc = l & 15;
    int grp = l >> 4;
    int pImg = y0 * W_ + x0;
    int pixBase = b * HW_ + pImg;

    const ush* qrowH = qHp + (size_t)(pixBase + lc) * HC_ + grp * 8;
    const ush* qrowL = qLp + (size_t)(pixBase + lc) * HC_ + grp * 8;
    bf16x8 qh[4], ql[4];
    #pragma unroll
    for (int ks = 0; ks < 4; ++ks) {
        qh[ks] = *(const bf16x8*)(qrowH + ks * 32);
        ql[ks] = *(const bf16x8*)(qrowL + ks * 32);
    }

    // ---- scores ----
    for (int idx = w; idx < 21; idx += 8) {
        int d = idx / 7, i = idx - 7 * d;
        int ry = min(max(y0 + i - 3, 0), H_ - 1);
        size_t rowOff = ((size_t)(b * DC_ + d) * HW_ + ry * W_) * HC_;
        const ush* psiRowH = psiHp + rowOff;
        const ush* psiRowL = psiLp + rowOff;
        #pragma unroll
        for (int f = 0; f < 2; ++f) {
            int c = f * 16 + lc;
            int px = min(max(x0 + c - 3, 0), W_ - 1);
            const ush* bpH = psiRowH + (size_t)px * HC_ + grp * 8;
            const ush* bpL = psiRowL + (size_t)px * HC_ + grp * 8;
            f32x4 acc = {0.f, 0.f, 0.f, 0.f};
            #pragma unroll
            for (int ks = 0; ks < 4; ++ks) {
                bf16x8 ph = *(const bf16x8*)(bpH + ks * 32);
                bf16x8 pl = *(const bf16x8*)(bpL + ks * 32);
                acc = __builtin_amdgcn_mfma_f32_16x16x32_bf16(qh[ks], ph, acc, 0, 0, 0);
                acc = __builtin_amdgcn_mfma_f32_16x16x32_bf16(qh[ks], pl, acc, 0, 0, 0);
                acc = __builtin_amdgcn_mfma_f32_16x16x32_bf16(ql[ks], ph, acc, 0, 0, 0);
            }
            #pragma unroll
            for (int r = 0; r < 4; ++r) {
                int p = grp * 4 + r;
                int j = c - p;
                if (j >= 0 && j < 7) S[(idx * 7 + j) * SST + p] = acc[r];
            }
        }
    }
    __syncthreads();

    // ---- softmax ----
    #pragma unroll
    for (int pi = 0; pi < 2; ++pi) {
        int p = w * 2 + pi;
        float s0 = S[l * SST + p];
        float s1 = S[(64 + l) * SST + p];
        float s2 = (l + 128 < K_) ? S[(128 + l) * SST + p] : -1e30f;
        float m = fmaxf(fmaxf(s0, s1), s2);
        #pragma unroll
        for (int off = 32; off; off >>= 1) m = fmaxf(m, __shfl_xor(m, off));
        float e0 = __expf(s0 - m), e1 = __expf(s1 - m), e2 = __expf(s2 - m);
        float sum = e0 + e1 + e2;
        #pragma unroll
        for (int off = 32; off; off >>= 1) sum += __shfl_xor(sum, off);
        float inv = 1.0f / sum;
        S[l * SST + p] = e0 * inv;
        S[(64 + l) * SST + p] = e1 * inv;
        if (l + 128 < K_) S[(128 + l) * SST + p] = e2 * inv;
    }
    __syncthreads();

    // ---- PV ----
    int hB = w * 16 + lc;
    f32x4 acc = {0.f, 0.f, 0.f, 0.f};
    for (int idx = 0; idx < 21; ++idx) {
        int d = idx / 7, i = idx - 7 * d;
        int ry = min(max(y0 + i - 3, 0), H_ - 1);
        unsigned au[4];
        #pragma unroll
        for (int rr = 0; rr < 4; ++rr) {
            int k0 = grp * 8 + rr * 2;
            int j0 = k0 - lc, j1 = k0 + 1 - lc;
            float v0 = (j0 >= 0 && j0 < 7) ? S[(idx * 7 + j0) * SST + lc] : 0.f;
            float v1 = (j1 >= 0 && j1 < 7) ? S[(idx * 7 + j1) * SST + lc] : 0.f;
            au[rr] = (unsigned)f2bf(v0) | ((unsigned)f2bf(v1) << 16);
        }
        union { unsigned u[4]; bf16x8 v; } af;
        af.u[0] = au[0]; af.u[1] = au[1]; af.u[2] = au[2]; af.u[3] = au[3];
        const ush* gb = g
            + (((size_t)(b * HC_ + hB) * DC_ + d) * H_ + ry) * GW + x0 + grp * 8;
        bf16x8 bg = *(const bf16x8*)gb;
        acc = __builtin_amdgcn_mfma_f32_16x16x32_bf16(af.v, bg, acc, 0, 0, 0);
    }
    // PV result -> LDS Y planes (y[p][h] hi/lo)
    #pragma unroll
    for (int r = 0; r < 4; ++r) {
        int p = grp * 4 + r;
        float v = acc[r];
        ush hh = f2bf(v);
        YH[p][hB] = hh;
        YL[p][hB] = f2bf(v - bf2f(hh));
    }
    __syncthreads();

    // ---- wy: wave w computes out-tiles 2w, 2w+1 (outs 32w..32w+31) ----
    #pragma unroll
    for (int oi = 0; oi < 2; ++oi) {
        int ot = w * 2 + oi;
        const ush* wrH = WwH + (size_t)(ot * 16 + lc) * HC_ + grp * 8;
        const ush* wrL = WwL + (size_t)(ot * 16 + lc) * HC_ + grp * 8;
        f32x4 a2 = {0.f, 0.f, 0.f, 0.f};
        #pragma unroll
        for (int ks = 0; ks < 4; ++ks) {
            bf16x8 bh = *(const bf16x8*)&YH[lc][ks * 32 + grp * 8];
            bf16x8 bl = *(const bf16x8*)&YL[lc][ks * 32 + grp * 8];
            bf16x8 aH = *(const bf16x8*)(wrH + ks * 32);
            bf16x8 aL = *(const bf16x8*)(wrL + ks * 32);
            a2 = __builtin_amdgcn_mfma_f32_16x16x32_bf16(aH, bh, a2, 0, 0, 0);
            a2 = __builtin_amdgcn_mfma_f32_16x16x32_bf16(aH, bl, a2, 0, 0, 0);
            a2 = __builtin_amdgcn_mfma_f32_16x16x32_bf16(aL, bh, a2, 0, 0, 0);
        }
        int o0 = ot * 16 + grp * 4;
        #pragma unroll
        for (int r2 = 0; r2 < 4; ++r2)
            wyO[(size_t)(b * C_ + o0 + r2) * HW_ + pImg + lc] = a2[r2];
    }
}

// ---------------------------------------------------------------------------
// 3) BN batch stats per channel -> folded scale/shift.  grid = 256
__global__ __launch_bounds__(256) void bn_stats_kernel(
    const float* __restrict__ wy, const float* __restrict__ gamma,
    const float* __restrict__ beta, float2* __restrict__ stats)
{
    int o = blockIdx.x;
    int tid = threadIdx.x;
    float s = 0.f, s2 = 0.f;
    for (int idx = tid; idx < NP_; idx += 256) {
        int b = idx / HW_;
        int p = idx - b * HW_;
        float v = wy[(size_t)(b * C_ + o) * HW_ + p];
        s += v;
        s2 = fmaf(v, v, s2);
    }
    #pragma unroll
    for (int off = 32; off; off >>= 1) {
        s  += __shfl_xor(s, off);
        s2 += __shfl_xor(s2, off);
    }
    __shared__ float ls[4], ls2[4];
    int wv = tid >> 6, lane = tid & 63;
    if (lane == 0) { ls[wv] = s; ls2[wv] = s2; }
    __syncthreads();
    if (tid == 0) {
        float S  = ls[0] + ls[1] + ls[2] + ls[3];
        float S2 = ls2[0] + ls2[1] + ls2[2] + ls2[3];
        float mean = S / (float)NP_;
        float var = fmaxf(S2 / (float)NP_ - mean * mean, 0.f);
        float rstd = rsqrtf(var + 1e-5f);
        float sc = gamma[o] * rstd;
        stats[o] = make_float2(sc, beta[o] - mean * sc);
    }
}

// ---------------------------------------------------------------------------
// 4) z = x + wy*scale + shift
__global__ __launch_bounds__(256) void final_kernel(
    const float* __restrict__ x, const float* __restrict__ wy,
    const float2* __restrict__ stats, float* __restrict__ out)
{
    int idx = blockIdx.x * 256 + threadIdx.x;
    int e0 = idx * 4;
    int c = (e0 / HW_) & (C_ - 1);
    float2 st = stats[c];
    float4 xv = *(const float4*)(x + e0);
    float4 wv = *(const float4*)(wy + e0);
    float4 o;
    o.x = fmaf(wv.x, st.x, xv.x + st.y);
    o.y = fmaf(wv.y, st.x, xv.y + st.y);
    o.z = fmaf(wv.z, st.x, xv.z + st.y);
    o.w = fmaf(wv.w, st.x, xv.w + st.y);
    *(float4*)(out + e0) = o;
}

extern "C" void kernel_launch(void* const* d_in, const int* in_sizes, int n_in,
                              void* d_out, int out_size, void* d_ws, size_t ws_size,
                              hipStream_t stream) {
    const float* x       = (const float*)d_in[0];
    const float* ctx     = (const float*)d_in[1];
    const float* theta_w = (const float*)d_in[2];
    const float* psi_w   = (const float*)d_in[3];
    const float* g_w     = (const float*)d_in[4];
    const float* W_w     = (const float*)d_in[5];
    // d_in[6] = W_b: unused, cancels exactly under training-mode BN
    const float* gamma   = (const float*)d_in[7];
    const float* beta    = (const float*)d_in[8];
    float* out = (float*)d_out;

    ush* ws = (ush*)d_ws;
    ush* qH    = ws;                     // 589824
    ush* qL    = qH + 589824;
    ush* psiH  = qL + 589824;            // 1769472
    ush* psiL  = psiH + 1769472;
    ush* gB    = psiL + 1769472;         // 2359296  [B,128,3,48,64] padded
    ush* gtmp  = gB + 2359296;           // 3538944  [B,128,3,48,48] unpadded
    ush* WpgH  = gtmp + 3538944;         // 65536
    ush* WpgL  = WpgH + 65536;
    ush* WqH   = WpgL + 65536;           // 32768
    ush* WqL   = WqH + 32768;
    ush* WwH   = WqL + 32768;            // 32768
    ush* WwL   = WwH + 32768;
    ush* ctxTH = WwL + 32768;            // 3538944
    ush* ctxTL = ctxTH + 3538944;
    ush* xTH   = ctxTL + 3538944;        // 1179648
    ush* xTL   = xTH + 1179648;
    float2* stats = (float2*)(xTL + 1179648);
    // alias (stream-ordered single-call lifetime, deterministic each call):
    float* wyB = (float*)ctxTH;          // 1179648 f32 <= ctxT region (proj done)

    prep_kernel<<<dim3(1280), 256, 0, stream>>>(ctx, x, psi_w, g_w, theta_w, W_w,
                                                ctxTH, ctxTL, xTH, xTL,
                                                WpgH, WpgL, WqH, WqL, WwH, WwL);
    proj4_kernel<<<dim3(1008), 256, 0, stream>>>(WpgH, WpgL, WqH, WqL,
                                                 ctxTH, ctxTL, xTH, xTL,
                                                 psiH, psiL, gtmp, qH, qL);
    pad2_kernel<<<dim3(1152), 256, 0, stream>>>(gtmp, gB);
    attn_wy_kernel<<<dim3(288), 512, 0, stream>>>(qH, qL, psiH, psiL, gB,
                                                  WwH, WwL, wyB);
    bn_stats_kernel<<<dim3(C_), 256, 0, stream>>>(wyB, gamma, beta, stats);
    final_kernel<<<dim3(B_ * C_ * HW_ / 4 / 256), 256, 0, stream>>>(x, wyB, stats, out);
}

// Round 13
// 78.613 us; speedup vs baseline: 1.5518x; 1.0025x over previous
//
#include <hip/hip_runtime.h>
#include <cmath>

#define B_   2
#define C_   256
#define HC_  128
#define DC_  3
#define H_   48
#define W_   48
#define HW_  (H_ * W_)      // 2304
#define NP_  (B_ * HW_)     // 4608
#define K_   (DC_ * 49)     // 147
#define GW   64             // padded g width (col = x+3, 16B-aligned rows)
#define SST  19             // S stride (words): PV read coeff -18*lc -> distinct banks
#define YST  152            // Y stride (ush): 304B rows, 16B-aligned

typedef unsigned short ush;
typedef __attribute__((ext_vector_type(8))) short bf16x8;
typedef __attribute__((ext_vector_type(8))) unsigned short ush8x;
typedef __attribute__((ext_vector_type(4))) float f32x4;
typedef __attribute__((ext_vector_type(4))) unsigned u32x4;

__device__ inline ush f2bf(float f) {
    union { float f; unsigned u; } v; v.f = f;
    unsigned r = v.u + 0x7FFF + ((v.u >> 16) & 1);
    return (ush)(r >> 16);
}
__device__ inline float bf2f(ush h) {
    union { unsigned u; float f; } v; v.u = ((unsigned)h) << 16;
    return v.f;
}
__device__ inline unsigned packhl(float f) {
    ush h = f2bf(f);
    ush l = f2bf(f - bf2f(h));
    return (unsigned)h | ((unsigned)l << 16);
}
__device__ __forceinline__ void gload16(const void* g, void* l) {
    __builtin_amdgcn_global_load_lds(
        (const __attribute__((address_space(1))) unsigned*)g,
        (__attribute__((address_space(3))) unsigned*)l, 16, 0, 0);
}

// ---------------------------------------------------------------------------
// 0) prep: blocks 0..1151 = transpose+split ctx/x -> ctxT/xT hi/lo;
//          blocks 1152..1279 = weight hi/lo split.
__global__ __launch_bounds__(256) void prep_kernel(
    const float* __restrict__ ctx, const float* __restrict__ x,
    const float* __restrict__ psi_w, const float* __restrict__ g_w,
    const float* __restrict__ theta_w, const float* __restrict__ Ww,
    ush* __restrict__ ctxTH, ush* __restrict__ ctxTL,
    ush* __restrict__ xTH, ush* __restrict__ xTL,
    ush* __restrict__ WpgH, ush* __restrict__ WpgL,
    ush* __restrict__ WqH, ush* __restrict__ WqL,
    ush* __restrict__ WwH, ush* __restrict__ WwL)
{
    __shared__ float T[64][65];
    int id = blockIdx.x;
    if (id >= 1152) {
        int idx = ((id - 1152) * 256 + threadIdx.x) * 4;
        float4 v;
        ush *dH, *dL;
        if (idx < 65536) {
            v = *(const float4*)(idx < 32768 ? psi_w + idx : g_w + (idx - 32768));
            dH = WpgH + idx; dL = WpgL + idx;
        } else if (idx < 98304) {
            v = *(const float4*)(theta_w + idx - 65536);
            dH = WqH + idx - 65536; dL = WqL + idx - 65536;
        } else {
            v = *(const float4*)(Ww + idx - 98304);
            dH = WwH + idx - 98304; dL = WwL + idx - 98304;
        }
        ushort4 h, l;
        h.x = f2bf(v.x); l.x = f2bf(v.x - bf2f(h.x));
        h.y = f2bf(v.y); l.y = f2bf(v.y - bf2f(h.y));
        h.z = f2bf(v.z); l.z = f2bf(v.z - bf2f(h.z));
        h.w = f2bf(v.w); l.w = f2bf(v.w - bf2f(h.w));
        *(ushort4*)dH = h; *(ushort4*)dL = l;
        return;
    }
    const float* src;
    ush *dH, *dL;
    size_t rowStride;
    if (id < 864) {
        int ct = id & 3, pt = (id >> 2) % 36, bd = id / 144;
        int b = bd / 3, d = bd % 3;
        int c0 = ct * 64, p0 = pt * 64;
        src = ctx + ((size_t)(b * 256 + c0) * 3 + d) * HW_ + p0;
        rowStride = 3 * HW_;
        size_t ob = ((size_t)(b * 3 + d) * HW_ + p0) * 256 + c0;
        dH = ctxTH + ob; dL = ctxTL + ob;
    } else {
        int id2 = id - 864;
        int ct = id2 & 3, pt = (id2 >> 2) % 36, b = id2 / 144;
        int c0 = ct * 64, p0 = pt * 64;
        src = x + (size_t)(b * 256 + c0) * HW_ + p0;
        rowStride = HW_;
        size_t ob = ((size_t)b * HW_ + p0) * 256 + c0;
        dH = xTH + ob; dL = xTL + ob;
    }
    int t = threadIdx.x;
    int cl = t >> 4, p4 = (t & 15) * 4;
    #pragma unroll
    for (int r = 0; r < 4; ++r) {
        int c = cl + r * 16;
        float4 v = *(const float4*)(src + (size_t)c * rowStride + p4);
        T[c][p4] = v.x; T[c][p4 + 1] = v.y; T[c][p4 + 2] = v.z; T[c][p4 + 3] = v.w;
    }
    __syncthreads();
    int pl = t >> 2, ch = t & 3;
    #pragma unroll
    for (int s = 0; s < 2; ++s) {
        int c8 = (ch + s * 4) * 8;
        ush8x vh, vl;
        #pragma unroll
        for (int i = 0; i < 8; ++i) {
            float f = T[c8 + i][pl];
            ush hh = f2bf(f);
            vh[i] = hh;
            vl[i] = f2bf(f - bf2f(hh));
        }
        *(ush8x*)(dH + (size_t)pl * 256 + c8) = vh;
        *(ush8x*)(dL + (size_t)pl * 256 + c8) = vl;
    }
}

// ---------------------------------------------------------------------------
// 1) proj4: m97-style MFMA GEMM with global_load_lds staging (unchanged).
__global__ __launch_bounds__(256) void proj4_kernel(
    const ush* __restrict__ WpgH, const ush* __restrict__ WpgL,
    const ush* __restrict__ WqH, const ush* __restrict__ WqL,
    const ush* __restrict__ ctxTH, const ush* __restrict__ ctxTL,
    const ush* __restrict__ xTH, const ush* __restrict__ xTL,
    ush* __restrict__ psiH, ush* __restrict__ psiL,
    ush* __restrict__ gtmp, ush* __restrict__ qH, ush* __restrict__ qL)
{
    __shared__ __align__(16) unsigned char LB[32768];  // A-H|A-L|B-H|B-L 8KB each

    int bid = blockIdx.x;
    int swz = (bid & 7) * 126 + (bid >> 3);   // 1008 = 8*126, XCD-contiguous
    int t = threadIdx.x, w = t >> 6, l = t & 63, lc = l & 15, grp = l >> 4;
    int mode, b, d, pxBase, otg;
    const ush *XH, *XL, *WH, *WL;
    if (swz < 864) {
        mode = 0; otg = swz & 3;               // 0,1: psi  2,3: g
        int rest = swz >> 2;                   // 0..215
        int pxt = rest % 36, bd = rest / 36;
        b = bd / 3; d = bd % 3;
        pxBase = pxt * 64;
        size_t xb = (size_t)(b * 3 + d) * HW_ * 256;
        XH = ctxTH + xb; XL = ctxTL + xb;
        WH = WpgH; WL = WpgL;
    } else {
        mode = 1;
        int id2 = swz - 864; otg = id2 & 1;
        int rest = id2 >> 1;                   // 0..71
        int pxt = rest % 36; b = rest / 36; d = 0;
        pxBase = pxt * 64;
        size_t xb = (size_t)b * HW_ * 256;
        XH = xTH + xb; XL = xTL + xb;
        WH = WqH; WL = WqL;
    }

    const ush* GSRC = (w == 0) ? WH : (w == 1) ? WL : (w == 2) ? XH : XL;
    int rowBase = (w < 2) ? (otg * 64) : pxBase;
    int r8 = l >> 3;
    int kg = (l & 7) ^ r8;
    unsigned char* ldsPlane = LB + w * 8192;

    f32x4 acc0 = {0,0,0,0}, acc1 = {0,0,0,0}, acc2 = {0,0,0,0}, acc3 = {0,0,0,0};

    for (int kst = 0; kst < 4; ++kst) {
        __syncthreads();
        #pragma unroll
        for (int wl = 0; wl < 8; ++wl) {
            int row = rowBase + wl * 8 + r8;
            gload16(GSRC + (size_t)row * 256 + kst * 64 + kg * 8,
                    ldsPlane + wl * 1024);
        }
        __syncthreads();

        #pragma unroll
        for (int ksub = 0; ksub < 2; ++ksub) {
            int sw = ((ksub * 4 + grp) ^ (lc & 7)) << 4;
            int brow = w * 16 + lc;
            bf16x8 bh = *(const bf16x8*)(LB + 16384 + brow * 128 + sw);
            bf16x8 bl = *(const bf16x8*)(LB + 24576 + brow * 128 + sw);
            #pragma unroll
            for (int ot = 0; ot < 4; ++ot) {
                int arow = ot * 16 + lc;
                bf16x8 ah = *(const bf16x8*)(LB +        arow * 128 + sw);
                bf16x8 al = *(const bf16x8*)(LB + 8192 + arow * 128 + sw);
                f32x4 a = (ot == 0) ? acc0 : (ot == 1) ? acc1 : (ot == 2) ? acc2 : acc3;
                a = __builtin_amdgcn_mfma_f32_16x16x32_bf16(ah, bh, a, 0, 0, 0);
                a = __builtin_amdgcn_mfma_f32_16x16x32_bf16(ah, bl, a, 0, 0, 0);
                a = __builtin_amdgcn_mfma_f32_16x16x32_bf16(al, bh, a, 0, 0, 0);
                if (ot == 0) acc0 = a; else if (ot == 1) acc1 = a;
                else if (ot == 2) acc2 = a; else acc3 = a;
            }
        }
    }

    __syncthreads();
    unsigned (*T)[68] = (unsigned(*)[68])LB;
    {
        u32x4 pv;
        pv[0] = packhl(acc0[0]); pv[1] = packhl(acc0[1]);
        pv[2] = packhl(acc0[2]); pv[3] = packhl(acc0[3]);
        *(u32x4*)&T[w * 16 + lc][0 * 16 + grp * 4] = pv;
        pv[0] = packhl(acc1[0]); pv[1] = packhl(acc1[1]);
        pv[2] = packhl(acc1[2]); pv[3] = packhl(acc1[3]);
        *(u32x4*)&T[w * 16 + lc][1 * 16 + grp * 4] = pv;
        pv[0] = packhl(acc2[0]); pv[1] = packhl(acc2[1]);
        pv[2] = packhl(acc2[2]); pv[3] = packhl(acc2[3]);
        *(u32x4*)&T[w * 16 + lc][2 * 16 + grp * 4] = pv;
        pv[0] = packhl(acc3[0]); pv[1] = packhl(acc3[1]);
        pv[2] = packhl(acc3[2]); pv[3] = packhl(acc3[3]);
        *(u32x4*)&T[w * 16 + lc][3 * 16 + grp * 4] = pv;
    }
    __syncthreads();

    if (mode == 1 || otg < 2) {
        ush* PH = (mode == 0) ? psiH : qH;
        ush* PL = (mode == 0) ? psiL : qL;
        #pragma unroll
        for (int it = 0; it < 2; ++it) {
            int idx = it * 256 + t;
            int pxl = idx >> 3, ch = idx & 7;
            u32x4 v0 = *(const u32x4*)&T[pxl][ch * 8];
            u32x4 v1 = *(const u32x4*)&T[pxl][ch * 8 + 4];
            ush8x hi, lo;
            #pragma unroll
            for (int i = 0; i < 4; ++i) {
                hi[i] = (ush)(v0[i] & 0xffffu); lo[i] = (ush)(v0[i] >> 16);
                hi[4 + i] = (ush)(v1[i] & 0xffffu); lo[4 + i] = (ush)(v1[i] >> 16);
            }
            int pix = pxBase + pxl;
            size_t base;
            if (mode == 0)
                base = ((size_t)(b * DC_ + d) * HW_ + pix) * HC_ + otg * 64 + ch * 8;
            else
                base = ((size_t)b * HW_ + pix) * HC_ + otg * 64 + ch * 8;
            *(ush8x*)&PH[base] = hi;
            *(ush8x*)&PL[base] = lo;
        }
    } else {
        #pragma unroll
        for (int it = 0; it < 2; ++it) {
            int idx = it * 256 + t;
            int ol = idx >> 3, pg = idx & 7;
            ush8x hv;
            #pragma unroll
            for (int i = 0; i < 8; ++i)
                hv[i] = (ush)(T[pg * 8 + i][ol] & 0xffffu);
            int og = (otg - 2) * 64 + ol;
            int pxg = pxBase + pg * 8;
            int yy = pxg / W_, xx = pxg - yy * W_;
            *(ush8x*)&gtmp[(((size_t)(b * HC_ + og) * DC_ + d) * H_ + yy) * W_ + xx] = hv;
        }
    }
}

// ---------------------------------------------------------------------------
// 1b) pad: gtmp rows (48) -> gB rows (64) with +3 shift and edge replication.
__global__ __launch_bounds__(256) void pad2_kernel(
    const ush* __restrict__ gtmp, ush* __restrict__ gB)
{
    __shared__ ush R[32][48];
    int blk = blockIdx.x, t = threadIdx.x;
    int r = t >> 3, ch = t & 7;
    size_t row = (size_t)blk * 32 + r;
    if (ch < 6)
        *(ush8x*)&R[r][ch * 8] = *(const ush8x*)&gtmp[row * W_ + ch * 8];
    __syncthreads();
    ush8x o;
    #pragma unroll
    for (int i = 0; i < 8; ++i) {
        int x = ch * 8 + i - 3;
        x = min(max(x, 0), W_ - 1);
        o[i] = R[r][x];
    }
    *(ush8x*)&gB[row * GW + ch * 8] = o;
}

// ---------------------------------------------------------------------------
// 2) FUSED attention + wy, register-batched operand loads:
//    scores: ph[4]/pl[4] arrays loaded BEFORE the 12-MFMA chain;
//    PV: bgb[2][7] double-buffered g-row prefetch (d unrolled);
//    wy: all 16 Ww loads issued before the Y barrier.
__global__ __launch_bounds__(512, 2) void attn_wy_kernel(
    const ush* __restrict__ qHp, const ush* __restrict__ qLp,
    const ush* __restrict__ psiHp, const ush* __restrict__ psiLp,
    const ush* __restrict__ g,
    const ush* __restrict__ WwH, const ush* __restrict__ WwL,
    float* __restrict__ wyO)
{
    __shared__ float S[147 * SST];
    __shared__ ush YH[16][YST], YL[16][YST];

    int bid = blockIdx.x;
    int tile = (bid & 7) * 36 + (bid >> 3);   // XCD-contiguous pixel rows
    int b = tile / 144;
    int tr = tile - b * 144;
    int y0 = tr / 3;
    int x0 = (tr % 3) * 16;

    int t = threadIdx.x;
    int w = t >> 6;
    int l = t & 63;
    int lc = l & 15;
    int grp = l >> 4;
    int pImg = y0 * W_ + x0;
    int pixBase = b * HW_ + pImg;

    const ush* qrowH = qHp + (size_t)(pixBase + lc) * HC_ + grp * 8;
    const ush* qrowL = qLp + (size_t)(pixBase + lc) * HC_ + grp * 8;
    bf16x8 qh[4], ql[4];
    #pragma unroll
    for (int ks = 0; ks < 4; ++ks) {
        qh[ks] = *(const bf16x8*)(qrowH + ks * 32);
        ql[ks] = *(const bf16x8*)(qrowL + ks * 32);
    }

    // ---- scores: batch 8 operand loads, then 12-MFMA chain ----
    for (int idx = w; idx < 21; idx += 8) {
        int d = idx / 7, i = idx - 7 * d;
        int ry = min(max(y0 + i - 3, 0), H_ - 1);
        size_t rowOff = ((size_t)(b * DC_ + d) * HW_ + ry * W_) * HC_;
        const ush* psiRowH = psiHp + rowOff;
        const ush* psiRowL = psiLp + rowOff;
        #pragma unroll
        for (int f = 0; f < 2; ++f) {
            int c = f * 16 + lc;
            int px = min(max(x0 + c - 3, 0), W_ - 1);
            const ush* bpH = psiRowH + (size_t)px * HC_ + grp * 8;
            const ush* bpL = psiRowL + (size_t)px * HC_ + grp * 8;
            bf16x8 ph[4], pl[4];
            #pragma unroll
            for (int ks = 0; ks < 4; ++ks) {
                ph[ks] = *(const bf16x8*)(bpH + ks * 32);
                pl[ks] = *(const bf16x8*)(bpL + ks * 32);
            }
            f32x4 acc = {0.f, 0.f, 0.f, 0.f};
            #pragma unroll
            for (int ks = 0; ks < 4; ++ks) {
                acc = __builtin_amdgcn_mfma_f32_16x16x32_bf16(qh[ks], ph[ks], acc, 0, 0, 0);
                acc = __builtin_amdgcn_mfma_f32_16x16x32_bf16(qh[ks], pl[ks], acc, 0, 0, 0);
                acc = __builtin_amdgcn_mfma_f32_16x16x32_bf16(ql[ks], ph[ks], acc, 0, 0, 0);
            }
            #pragma unroll
            for (int r = 0; r < 4; ++r) {
                int p = grp * 4 + r;
                int j = c - p;
                if (j >= 0 && j < 7) S[(idx * 7 + j) * SST + p] = acc[r];
            }
        }
    }
    __syncthreads();

    // ---- softmax ----
    #pragma unroll
    for (int pi = 0; pi < 2; ++pi) {
        int p = w * 2 + pi;
        float s0 = S[l * SST + p];
        float s1 = S[(64 + l) * SST + p];
        float s2 = (l + 128 < K_) ? S[(128 + l) * SST + p] : -1e30f;
        float m = fmaxf(fmaxf(s0, s1), s2);
        #pragma unroll
        for (int off = 32; off; off >>= 1) m = fmaxf(m, __shfl_xor(m, off));
        float e0 = __expf(s0 - m), e1 = __expf(s1 - m), e2 = __expf(s2 - m);
        float sum = e0 + e1 + e2;
        #pragma unroll
        for (int off = 32; off; off >>= 1) sum += __shfl_xor(sum, off);
        float inv = 1.0f / sum;
        S[l * SST + p] = e0 * inv;
        S[(64 + l) * SST + p] = e1 * inv;
        if (l + 128 < K_) S[(128 + l) * SST + p] = e2 * inv;
    }
    __syncthreads();

    // ---- PV: double-buffered g prefetch ----
    int hB = w * 16 + lc;
    const ush* gBase = g + (size_t)(b * HC_ + hB) * DC_ * H_ * GW + x0 + grp * 8;
    bf16x8 bgb[2][7];
    #pragma unroll
    for (int i = 0; i < 7; ++i) {
        int ry = min(max(y0 + i - 3, 0), H_ - 1);
        bgb[0][i] = *(const bf16x8*)(gBase + (size_t)ry * GW);
    }
    f32x4 acc = {0.f, 0.f, 0.f, 0.f};
    #pragma unroll
    for (int d = 0; d < 3; ++d) {
        if (d < 2) {
            #pragma unroll
            for (int i = 0; i < 7; ++i) {
                int ry = min(max(y0 + i - 3, 0), H_ - 1);
                bgb[(d + 1) & 1][i] = *(const bf16x8*)(gBase + (size_t)((d + 1) * H_ + ry) * GW);
            }
        }
        #pragma unroll
        for (int i = 0; i < 7; ++i) {
            int idx = d * 7 + i;
            unsigned au[4];
            #pragma unroll
            for (int rr = 0; rr < 4; ++rr) {
                int k0 = grp * 8 + rr * 2;
                int j0 = k0 - lc, j1 = k0 + 1 - lc;
                float v0 = (j0 >= 0 && j0 < 7) ? S[(idx * 7 + j0) * SST + lc] : 0.f;
                float v1 = (j1 >= 0 && j1 < 7) ? S[(idx * 7 + j1) * SST + lc] : 0.f;
                au[rr] = (unsigned)f2bf(v0) | ((unsigned)f2bf(v1) << 16);
            }
            union { unsigned u[4]; bf16x8 v; } af;
            af.u[0] = au[0]; af.u[1] = au[1]; af.u[2] = au[2]; af.u[3] = au[3];
            acc = __builtin_amdgcn_mfma_f32_16x16x32_bf16(af.v, bgb[d & 1][i], acc, 0, 0, 0);
        }
    }
    // PV result -> LDS Y planes (y[p][h] hi/lo)
    #pragma unroll
    for (int r = 0; r < 4; ++r) {
        int p = grp * 4 + r;
        float v = acc[r];
        ush hh = f2bf(v);
        YH[p][hB] = hh;
        YL[p][hB] = f2bf(v - bf2f(hh));
    }

    // issue wy weight loads BEFORE the barrier (resolve under barrier wait)
    bf16x8 wH[2][4], wL[2][4];
    #pragma unroll
    for (int oi = 0; oi < 2; ++oi) {
        int ot = w * 2 + oi;
        const ush* wrH = WwH + (size_t)(ot * 16 + lc) * HC_ + grp * 8;
        const ush* wrL = WwL + (size_t)(ot * 16 + lc) * HC_ + grp * 8;
        #pragma unroll
        for (int ks = 0; ks < 4; ++ks) {
            wH[oi][ks] = *(const bf16x8*)(wrH + ks * 32);
            wL[oi][ks] = *(const bf16x8*)(wrL + ks * 32);
        }
    }
    __syncthreads();

    // ---- wy: wave w computes out-tiles 2w, 2w+1 ----
    #pragma unroll
    for (int oi = 0; oi < 2; ++oi) {
        f32x4 a2 = {0.f, 0.f, 0.f, 0.f};
        #pragma unroll
        for (int ks = 0; ks < 4; ++ks) {
            bf16x8 bh = *(const bf16x8*)&YH[lc][ks * 32 + grp * 8];
            bf16x8 bl = *(const bf16x8*)&YL[lc][ks * 32 + grp * 8];
            a2 = __builtin_amdgcn_mfma_f32_16x16x32_bf16(wH[oi][ks], bh, a2, 0, 0, 0);
            a2 = __builtin_amdgcn_mfma_f32_16x16x32_bf16(wH[oi][ks], bl, a2, 0, 0, 0);
            a2 = __builtin_amdgcn_mfma_f32_16x16x32_bf16(wL[oi][ks], bh, a2, 0, 0, 0);
        }
        int o0 = (w * 2 + oi) * 16 + grp * 4;
        #pragma unroll
        for (int r2 = 0; r2 < 4; ++r2)
            wyO[(size_t)(b * C_ + o0 + r2) * HW_ + pImg + lc] = a2[r2];
    }
}

// ---------------------------------------------------------------------------
// 3) BN batch stats per channel -> folded scale/shift.  grid = 256
__global__ __launch_bounds__(256) void bn_stats_kernel(
    const float* __restrict__ wy, const float* __restrict__ gamma,
    const float* __restrict__ beta, float2* __restrict__ stats)
{
    int o = blockIdx.x;
    int tid = threadIdx.x;
    float s = 0.f, s2 = 0.f;
    for (int idx = tid; idx < NP_; idx += 256) {
        int b = idx / HW_;
        int p = idx - b * HW_;
        float v = wy[(size_t)(b * C_ + o) * HW_ + p];
        s += v;
        s2 = fmaf(v, v, s2);
    }
    #pragma unroll
    for (int off = 32; off; off >>= 1) {
        s  += __shfl_xor(s, off);
        s2 += __shfl_xor(s2, off);
    }
    __shared__ float ls[4], ls2[4];
    int wv = tid >> 6, lane = tid & 63;
    if (lane == 0) { ls[wv] = s; ls2[wv] = s2; }
    __syncthreads();
    if (tid == 0) {
        float S  = ls[0] + ls[1] + ls[2] + ls[3];
        float S2 = ls2[0] + ls2[1] + ls2[2] + ls2[3];
        float mean = S / (float)NP_;
        float var = fmaxf(S2 / (float)NP_ - mean * mean, 0.f);
        float rstd = rsqrtf(var + 1e-5f);
        float sc = gamma[o] * rstd;
        stats[o] = make_float2(sc, beta[o] - mean * sc);
    }
}

// ---------------------------------------------------------------------------
// 4) z = x + wy*scale + shift
__global__ __launch_bounds__(256) void final_kernel(
    const float* __restrict__ x, const float* __restrict__ wy,
    const float2* __restrict__ stats, float* __restrict__ out)
{
    int idx = blockIdx.x * 256 + threadIdx.x;
    int e0 = idx * 4;
    int c = (e0 / HW_) & (C_ - 1);
    float2 st = stats[c];
    float4 xv = *(const float4*)(x + e0);
    float4 wv = *(const float4*)(wy + e0);
    float4 o;
    o.x = fmaf(wv.x, st.x, xv.x + st.y);
    o.y = fmaf(wv.y, st.x, xv.y + st.y);
    o.z = fmaf(wv.z, st.x, xv.z + st.y);
    o.w = fmaf(wv.w, st.x, xv.w + st.y);
    *(float4*)(out + e0) = o;
}

extern "C" void kernel_launch(void* const* d_in, const int* in_sizes, int n_in,
                              void* d_out, int out_size, void* d_ws, size_t ws_size,
                              hipStream_t stream) {
    const float* x       = (const float*)d_in[0];
    const float* ctx     = (const float*)d_in[1];
    const float* theta_w = (const float*)d_in[2];
    const float* psi_w   = (const float*)d_in[3];
    const float* g_w     = (const float*)d_in[4];
    const float* W_w     = (const float*)d_in[5];
    // d_in[6] = W_b: unused, cancels exactly under training-mode BN
    const float* gamma   = (const float*)d_in[7];
    const float* beta    = (const float*)d_in[8];
    float* out = (float*)d_out;

    ush* ws = (ush*)d_ws;
    ush* qH    = ws;                     // 589824
    ush* qL    = qH + 589824;
    ush* psiH  = qL + 589824;            // 1769472
    ush* psiL  = psiH + 1769472;
    ush* gB    = psiL + 1769472;         // 2359296  [B,128,3,48,64] padded
    ush* gtmp  = gB + 2359296;           // 3538944  [B,128,3,48,48] unpadded
    ush* WpgH  = gtmp + 3538944;         // 65536
    ush* WpgL  = WpgH + 65536;
    ush* WqH   = WpgL + 65536;           // 32768
    ush* WqL   = WqH + 32768;
    ush* WwH   = WqL + 32768;            // 32768
    ush* WwL   = WwH + 32768;
    ush* ctxTH = WwL + 32768;            // 3538944
    ush* ctxTL = ctxTH + 3538944;
    ush* xTH   = ctxTL + 3538944;        // 1179648
    ush* xTL   = xTH + 1179648;
    float2* stats = (float2*)(xTL + 1179648);
    // alias (stream-ordered single-call lifetime, deterministic each call):
    float* wyB = (float*)ctxTH;          // 1179648 f32 <= ctxT region (proj done)

    prep_kernel<<<dim3(1280), 256, 0, stream>>>(ctx, x, psi_w, g_w, theta_w, W_w,
                                                ctxTH, ctxTL, xTH, xTL,
                                                WpgH, WpgL, WqH, WqL, WwH, WwL);
    proj4_kernel<<<dim3(1008), 256, 0, stream>>>(WpgH, WpgL, WqH, WqL,
                                                 ctxTH, ctxTL, xTH, xTL,
                                                 psiH, psiL, gtmp, qH, qL);
    pad2_kernel<<<dim3(1152), 256, 0, stream>>>(gtmp, gB);
    attn_wy_kernel<<<dim3(288), 512, 0, stream>>>(qH, qL, psiH, psiL, gB,
                                                  WwH, WwL, wyB);
    bn_stats_kernel<<<dim3(C_), 256, 0, stream>>>(wyB, gamma, beta, stats);
    final_kernel<<<dim3(B_ * C_ * HW_ / 4 / 256), 256, 0, stream>>>(x, wyB, stats, out);
}

// Round 14
// 77.552 us; speedup vs baseline: 1.5731x; 1.0137x over previous
//
#include <hip/hip_runtime.h>
#include <cmath>

#define B_   2
#define C_   256
#define HC_  128
#define DC_  3
#define H_   48
#define W_   48
#define HW_  (H_ * W_)      // 2304
#define NP_  (B_ * HW_)     // 4608
#define K_   (DC_ * 49)     // 147
#define GW   64             // padded g width (col = x+3, 16B-aligned rows)
#define SST  19             // S stride (words)
#define YST  152            // Y stride (ush)

typedef unsigned short ush;
typedef __attribute__((ext_vector_type(8))) short bf16x8;
typedef __attribute__((ext_vector_type(8))) unsigned short ush8x;
typedef __attribute__((ext_vector_type(4))) float f32x4;
typedef __attribute__((ext_vector_type(4))) unsigned u32x4;

__device__ inline ush f2bf(float f) {
    union { float f; unsigned u; } v; v.f = f;
    unsigned r = v.u + 0x7FFF + ((v.u >> 16) & 1);
    return (ush)(r >> 16);
}
__device__ inline float bf2f(ush h) {
    union { unsigned u; float f; } v; v.u = ((unsigned)h) << 16;
    return v.f;
}
__device__ inline unsigned packhl(float f) {
    ush h = f2bf(f);
    ush l = f2bf(f - bf2f(h));
    return (unsigned)h | ((unsigned)l << 16);
}
__device__ __forceinline__ void gload16(const void* g, void* l) {
    __builtin_amdgcn_global_load_lds(
        (const __attribute__((address_space(1))) unsigned*)g,
        (__attribute__((address_space(3))) unsigned*)l, 16, 0, 0);
}

// ---------------------------------------------------------------------------
// 0) prep: transpose+split ctx/x; weight hi/lo split. (unchanged)
__global__ __launch_bounds__(256) void prep_kernel(
    const float* __restrict__ ctx, const float* __restrict__ x,
    const float* __restrict__ psi_w, const float* __restrict__ g_w,
    const float* __restrict__ theta_w, const float* __restrict__ Ww,
    ush* __restrict__ ctxTH, ush* __restrict__ ctxTL,
    ush* __restrict__ xTH, ush* __restrict__ xTL,
    ush* __restrict__ WpgH, ush* __restrict__ WpgL,
    ush* __restrict__ WqH, ush* __restrict__ WqL,
    ush* __restrict__ WwH, ush* __restrict__ WwL)
{
    __shared__ float T[64][65];
    int id = blockIdx.x;
    if (id >= 1152) {
        int idx = ((id - 1152) * 256 + threadIdx.x) * 4;
        float4 v;
        ush *dH, *dL;
        if (idx < 65536) {
            v = *(const float4*)(idx < 32768 ? psi_w + idx : g_w + (idx - 32768));
            dH = WpgH + idx; dL = WpgL + idx;
        } else if (idx < 98304) {
            v = *(const float4*)(theta_w + idx - 65536);
            dH = WqH + idx - 65536; dL = WqL + idx - 65536;
        } else {
            v = *(const float4*)(Ww + idx - 98304);
            dH = WwH + idx - 98304; dL = WwL + idx - 98304;
        }
        ushort4 h, l;
        h.x = f2bf(v.x); l.x = f2bf(v.x - bf2f(h.x));
        h.y = f2bf(v.y); l.y = f2bf(v.y - bf2f(h.y));
        h.z = f2bf(v.z); l.z = f2bf(v.z - bf2f(h.z));
        h.w = f2bf(v.w); l.w = f2bf(v.w - bf2f(h.w));
        *(ushort4*)dH = h; *(ushort4*)dL = l;
        return;
    }
    const float* src;
    ush *dH, *dL;
    size_t rowStride;
    if (id < 864) {
        int ct = id & 3, pt = (id >> 2) % 36, bd = id / 144;
        int b = bd / 3, d = bd % 3;
        int c0 = ct * 64, p0 = pt * 64;
        src = ctx + ((size_t)(b * 256 + c0) * 3 + d) * HW_ + p0;
        rowStride = 3 * HW_;
        size_t ob = ((size_t)(b * 3 + d) * HW_ + p0) * 256 + c0;
        dH = ctxTH + ob; dL = ctxTL + ob;
    } else {
        int id2 = id - 864;
        int ct = id2 & 3, pt = (id2 >> 2) % 36, b = id2 / 144;
        int c0 = ct * 64, p0 = pt * 64;
        src = x + (size_t)(b * 256 + c0) * HW_ + p0;
        rowStride = HW_;
        size_t ob = ((size_t)b * HW_ + p0) * 256 + c0;
        dH = xTH + ob; dL = xTL + ob;
    }
    int t = threadIdx.x;
    int cl = t >> 4, p4 = (t & 15) * 4;
    #pragma unroll
    for (int r = 0; r < 4; ++r) {
        int c = cl + r * 16;
        float4 v = *(const float4*)(src + (size_t)c * rowStride + p4);
        T[c][p4] = v.x; T[c][p4 + 1] = v.y; T[c][p4 + 2] = v.z; T[c][p4 + 3] = v.w;
    }
    __syncthreads();
    int pl = t >> 2, ch = t & 3;
    #pragma unroll
    for (int s = 0; s < 2; ++s) {
        int c8 = (ch + s * 4) * 8;
        ush8x vh, vl;
        #pragma unroll
        for (int i = 0; i < 8; ++i) {
            float f = T[c8 + i][pl];
            ush hh = f2bf(f);
            vh[i] = hh;
            vl[i] = f2bf(f - bf2f(hh));
        }
        *(ush8x*)(dH + (size_t)pl * 256 + c8) = vh;
        *(ush8x*)(dL + (size_t)pl * 256 + c8) = vl;
    }
}

// ---------------------------------------------------------------------------
// 1) proj4 (unchanged)
__global__ __launch_bounds__(256) void proj4_kernel(
    const ush* __restrict__ WpgH, const ush* __restrict__ WpgL,
    const ush* __restrict__ WqH, const ush* __restrict__ WqL,
    const ush* __restrict__ ctxTH, const ush* __restrict__ ctxTL,
    const ush* __restrict__ xTH, const ush* __restrict__ xTL,
    ush* __restrict__ psiH, ush* __restrict__ psiL,
    ush* __restrict__ gtmp, ush* __restrict__ qH, ush* __restrict__ qL)
{
    __shared__ __align__(16) unsigned char LB[32768];

    int bid = blockIdx.x;
    int swz = (bid & 7) * 126 + (bid >> 3);
    int t = threadIdx.x, w = t >> 6, l = t & 63, lc = l & 15, grp = l >> 4;
    int mode, b, d, pxBase, otg;
    const ush *XH, *XL, *WH, *WL;
    if (swz < 864) {
        mode = 0; otg = swz & 3;
        int rest = swz >> 2;
        int pxt = rest % 36, bd = rest / 36;
        b = bd / 3; d = bd % 3;
        pxBase = pxt * 64;
        size_t xb = (size_t)(b * 3 + d) * HW_ * 256;
        XH = ctxTH + xb; XL = ctxTL + xb;
        WH = WpgH; WL = WpgL;
    } else {
        mode = 1;
        int id2 = swz - 864; otg = id2 & 1;
        int rest = id2 >> 1;
        int pxt = rest % 36; b = rest / 36; d = 0;
        pxBase = pxt * 64;
        size_t xb = (size_t)b * HW_ * 256;
        XH = xTH + xb; XL = xTL + xb;
        WH = WqH; WL = WqL;
    }

    const ush* GSRC = (w == 0) ? WH : (w == 1) ? WL : (w == 2) ? XH : XL;
    int rowBase = (w < 2) ? (otg * 64) : pxBase;
    int r8 = l >> 3;
    int kg = (l & 7) ^ r8;
    unsigned char* ldsPlane = LB + w * 8192;

    f32x4 acc0 = {0,0,0,0}, acc1 = {0,0,0,0}, acc2 = {0,0,0,0}, acc3 = {0,0,0,0};

    for (int kst = 0; kst < 4; ++kst) {
        __syncthreads();
        #pragma unroll
        for (int wl = 0; wl < 8; ++wl) {
            int row = rowBase + wl * 8 + r8;
            gload16(GSRC + (size_t)row * 256 + kst * 64 + kg * 8,
                    ldsPlane + wl * 1024);
        }
        __syncthreads();

        #pragma unroll
        for (int ksub = 0; ksub < 2; ++ksub) {
            int sw = ((ksub * 4 + grp) ^ (lc & 7)) << 4;
            int brow = w * 16 + lc;
            bf16x8 bh = *(const bf16x8*)(LB + 16384 + brow * 128 + sw);
            bf16x8 bl = *(const bf16x8*)(LB + 24576 + brow * 128 + sw);
            #pragma unroll
            for (int ot = 0; ot < 4; ++ot) {
                int arow = ot * 16 + lc;
                bf16x8 ah = *(const bf16x8*)(LB +        arow * 128 + sw);
                bf16x8 al = *(const bf16x8*)(LB + 8192 + arow * 128 + sw);
                f32x4 a = (ot == 0) ? acc0 : (ot == 1) ? acc1 : (ot == 2) ? acc2 : acc3;
                a = __builtin_amdgcn_mfma_f32_16x16x32_bf16(ah, bh, a, 0, 0, 0);
                a = __builtin_amdgcn_mfma_f32_16x16x32_bf16(ah, bl, a, 0, 0, 0);
                a = __builtin_amdgcn_mfma_f32_16x16x32_bf16(al, bh, a, 0, 0, 0);
                if (ot == 0) acc0 = a; else if (ot == 1) acc1 = a;
                else if (ot == 2) acc2 = a; else acc3 = a;
            }
        }
    }

    __syncthreads();
    unsigned (*T)[68] = (unsigned(*)[68])LB;
    {
        u32x4 pv;
        pv[0] = packhl(acc0[0]); pv[1] = packhl(acc0[1]);
        pv[2] = packhl(acc0[2]); pv[3] = packhl(acc0[3]);
        *(u32x4*)&T[w * 16 + lc][0 * 16 + grp * 4] = pv;
        pv[0] = packhl(acc1[0]); pv[1] = packhl(acc1[1]);
        pv[2] = packhl(acc1[2]); pv[3] = packhl(acc1[3]);
        *(u32x4*)&T[w * 16 + lc][1 * 16 + grp * 4] = pv;
        pv[0] = packhl(acc2[0]); pv[1] = packhl(acc2[1]);
        pv[2] = packhl(acc2[2]); pv[3] = packhl(acc2[3]);
        *(u32x4*)&T[w * 16 + lc][2 * 16 + grp * 4] = pv;
        pv[0] = packhl(acc3[0]); pv[1] = packhl(acc3[1]);
        pv[2] = packhl(acc3[2]); pv[3] = packhl(acc3[3]);
        *(u32x4*)&T[w * 16 + lc][3 * 16 + grp * 4] = pv;
    }
    __syncthreads();

    if (mode == 1 || otg < 2) {
        ush* PH = (mode == 0) ? psiH : qH;
        ush* PL = (mode == 0) ? psiL : qL;
        #pragma unroll
        for (int it = 0; it < 2; ++it) {
            int idx = it * 256 + t;
            int pxl = idx >> 3, ch = idx & 7;
            u32x4 v0 = *(const u32x4*)&T[pxl][ch * 8];
            u32x4 v1 = *(const u32x4*)&T[pxl][ch * 8 + 4];
            ush8x hi, lo;
            #pragma unroll
            for (int i = 0; i < 4; ++i) {
                hi[i] = (ush)(v0[i] & 0xffffu); lo[i] = (ush)(v0[i] >> 16);
                hi[4 + i] = (ush)(v1[i] & 0xffffu); lo[4 + i] = (ush)(v1[i] >> 16);
            }
            int pix = pxBase + pxl;
            size_t base;
            if (mode == 0)
                base = ((size_t)(b * DC_ + d) * HW_ + pix) * HC_ + otg * 64 + ch * 8;
            else
                base = ((size_t)b * HW_ + pix) * HC_ + otg * 64 + ch * 8;
            *(ush8x*)&PH[base] = hi;
            *(ush8x*)&PL[base] = lo;
        }
    } else {
        #pragma unroll
        for (int it = 0; it < 2; ++it) {
            int idx = it * 256 + t;
            int ol = idx >> 3, pg = idx & 7;
            ush8x hv;
            #pragma unroll
            for (int i = 0; i < 8; ++i)
                hv[i] = (ush)(T[pg * 8 + i][ol] & 0xffffu);
            int og = (otg - 2) * 64 + ol;
            int pxg = pxBase + pg * 8;
            int yy = pxg / W_, xx = pxg - yy * W_;
            *(ush8x*)&gtmp[(((size_t)(b * HC_ + og) * DC_ + d) * H_ + yy) * W_ + xx] = hv;
        }
    }
}

// ---------------------------------------------------------------------------
// 1b) pad (unchanged)
__global__ __launch_bounds__(256) void pad2_kernel(
    const ush* __restrict__ gtmp, ush* __restrict__ gB)
{
    __shared__ ush R[32][48];
    int blk = blockIdx.x, t = threadIdx.x;
    int r = t >> 3, ch = t & 7;
    size_t row = (size_t)blk * 32 + r;
    if (ch < 6)
        *(ush8x*)&R[r][ch * 8] = *(const ush8x*)&gtmp[row * W_ + ch * 8];
    __syncthreads();
    ush8x o;
    #pragma unroll
    for (int i = 0; i < 8; ++i) {
        int x = ch * 8 + i - 3;
        x = min(max(x, 0), W_ - 1);
        o[i] = R[r][x];
    }
    *(ush8x*)&gB[row * GW + ch * 8] = o;
}

// ---------------------------------------------------------------------------
// 2) FUSED attention + wy with global_load_lds staging of q, psi, g.
//    Dynamic LDS layout (143808 B):
//      [0..11200)        S (147*19 f32)
//      [11200..97216)    psi dbuf 2x43008  (aliased later by g dbuf 2x57344)
//      [125888..135616)  YH/YL (16 x 152 ush each)
//      [135616..143808)  QS (q staged, hi+lo)
__global__ __launch_bounds__(512) void attn_wy_kernel(
    const ush* __restrict__ qHp, const ush* __restrict__ qLp,
    const ush* __restrict__ psiHp, const ush* __restrict__ psiLp,
    const ush* __restrict__ g,
    const ush* __restrict__ WwH, const ush* __restrict__ WwL,
    float* __restrict__ wyO)
{
    extern __shared__ __align__(16) unsigned char DLB[];
    float* S = (float*)DLB;
    unsigned char* PS0 = DLB + 11200;
    unsigned char* PS1 = DLB + 11200 + 43008;
    unsigned char* GB0 = DLB + 11200;
    unsigned char* GB1 = DLB + 11200 + 57344;
    ush (*YH)[YST] = (ush(*)[YST])(DLB + 125888);
    ush (*YL)[YST] = (ush(*)[YST])(DLB + 125888 + 16 * YST * 2);
    unsigned char* QS = DLB + 135616;

    int bid = blockIdx.x;
    int tile = (bid & 7) * 36 + (bid >> 3);   // XCD-contiguous pixel rows
    int b = tile / 144;
    int tr = tile - b * 144;
    int y0 = tr / 3;
    int x0 = (tr % 3) * 16;

    int t = threadIdx.x;
    int w = t >> 6;
    int l = t & 63;
    int lc = l & 15;
    int grp = l >> 4;
    int pImg = y0 * W_ + x0;
    int pixBase = b * HW_ + pImg;

    // ---- staging lambdas ----
    auto stagePsi = [&](int d, int plane, unsigned char* PB) {
        const ush* SRC = plane ? psiLp : psiHp;
        size_t base = (size_t)(b * 3 + d) * HW_ * 128;
        #pragma unroll
        for (int it = 0; it < 6; ++it) {
            if (it < 5 || w < 2) {
                int cnk = it * 512 + t;
                int i = cnk / 384;
                int r = cnk - i * 384;
                int pxp = r >> 4, s = r & 15;
                int px = min(max(x0 - 3 + pxp, 0), W_ - 1);
                int ry = min(max(y0 + i - 3, 0), H_ - 1);
                gload16(SRC + base + (size_t)(ry * W_ + px) * 128
                            + ((s ^ (pxp & 15)) << 3),
                        PB + it * 8192 + w * 1024);
            }
        }
    };
    auto stageG = [&](int d, unsigned char* GBp) {
        int hh = w * 16 + (l >> 2);
        int pxc = l & 3;
        size_t rowb = ((size_t)(b * HC_ + hh) * DC_ + d) * (H_ * GW);
        #pragma unroll
        for (int it = 0; it < 7; ++it) {
            int ry = min(max(y0 + it - 3, 0), H_ - 1);
            gload16(g + rowb + (size_t)ry * GW + x0 + pxc * 8,
                    GBp + w * 7168 + it * 1024);
        }
    };

    // ---- prologue: stage q + psi pass0 ----
    {
        int plane = t >> 8, px = (t >> 4) & 15, s = t & 15;
        const ush* SRCq = plane ? qLp : qHp;
        gload16(SRCq + (size_t)(pixBase + px) * 128 + ((s ^ px) << 3),
                QS + w * 1024);
    }
    stagePsi(0, 0, PS0);
    __syncthreads();

    // q frags from LDS
    bf16x8 qh[4], ql[4];
    #pragma unroll
    for (int ks = 0; ks < 4; ++ks) {
        qh[ks] = *(const bf16x8*)(QS + lc * 256 + (((grp + 4 * ks) ^ lc) << 4));
        ql[ks] = *(const bf16x8*)(QS + 4096 + lc * 256 + (((grp + 4 * ks) ^ lc) << 4));
    }

    // ---- scores: 6 passes (d x plane), double-buffered psi staging ----
    #pragma unroll
    for (int p = 0; p < 6; ++p) {
        int d = p >> 1, plane = p & 1;
        if (p < 5)
            stagePsi((p + 1) >> 1, (p + 1) & 1, ((p + 1) & 1) ? PS1 : PS0);
        unsigned char* CUR = (p & 1) ? PS1 : PS0;
        for (int j = w; j < 14; j += 8) {
            int i = j >> 1, f = j & 1;
            int c = f * 16 + lc;
            f32x4 acc = {0.f, 0.f, 0.f, 0.f};
            #pragma unroll
            for (int ks = 0; ks < 4; ++ks) {
                bf16x8 bfrag = *(const bf16x8*)(CUR + i * 6144 + c * 256
                                + (((grp + 4 * ks) ^ lc) << 4));
                acc = __builtin_amdgcn_mfma_f32_16x16x32_bf16(qh[ks], bfrag, acc, 0, 0, 0);
                if (plane == 0)
                    acc = __builtin_amdgcn_mfma_f32_16x16x32_bf16(ql[ks], bfrag, acc, 0, 0, 0);
            }
            #pragma unroll
            for (int r = 0; r < 4; ++r) {
                int pp = grp * 4 + r;
                int j2 = c - pp;
                if (j2 >= 0 && j2 < 7) {
                    int slot = (d * 49 + i * 7 + j2) * SST + pp;
                    if (plane == 0) S[slot] = acc[r];
                    else S[slot] += acc[r];
                }
            }
        }
        __syncthreads();
    }

    // ---- stage g[0] (psi buffers dead), softmax overlaps the DMA ----
    stageG(0, GB0);
    #pragma unroll
    for (int pi = 0; pi < 2; ++pi) {
        int p = w * 2 + pi;
        float s0 = S[l * SST + p];
        float s1 = S[(64 + l) * SST + p];
        float s2 = (l + 128 < K_) ? S[(128 + l) * SST + p] : -1e30f;
        float m = fmaxf(fmaxf(s0, s1), s2);
        #pragma unroll
        for (int off = 32; off; off >>= 1) m = fmaxf(m, __shfl_xor(m, off));
        float e0 = __expf(s0 - m), e1 = __expf(s1 - m), e2 = __expf(s2 - m);
        float sum = e0 + e1 + e2;
        #pragma unroll
        for (int off = 32; off; off >>= 1) sum += __shfl_xor(sum, off);
        float inv = 1.0f / sum;
        S[l * SST + p] = e0 * inv;
        S[(64 + l) * SST + p] = e1 * inv;
        if (l + 128 < K_) S[(128 + l) * SST + p] = e2 * inv;
    }
    __syncthreads();

    // ---- PV: g staged per-d, double-buffered ----
    int hB = w * 16 + lc;
    f32x4 acc = {0.f, 0.f, 0.f, 0.f};
    #pragma unroll
    for (int d = 0; d < 3; ++d) {
        if (d < 2) stageG(d + 1, ((d + 1) & 1) ? GB1 : GB0);
        unsigned char* GBc = (d & 1) ? GB1 : GB0;
        #pragma unroll
        for (int i = 0; i < 7; ++i) {
            int idx = d * 7 + i;
            unsigned au[4];
            #pragma unroll
            for (int rr = 0; rr < 4; ++rr) {
                int k0 = grp * 8 + rr * 2;
                int j0 = k0 - lc, j1 = k0 + 1 - lc;
                float v0 = (j0 >= 0 && j0 < 7) ? S[(idx * 7 + j0) * SST + lc] : 0.f;
                float v1 = (j1 >= 0 && j1 < 7) ? S[(idx * 7 + j1) * SST + lc] : 0.f;
                au[rr] = (unsigned)f2bf(v0) | ((unsigned)f2bf(v1) << 16);
            }
            union { unsigned u[4]; bf16x8 v; } af;
            af.u[0] = au[0]; af.u[1] = au[1]; af.u[2] = au[2]; af.u[3] = au[3];
            bf16x8 bg = *(const bf16x8*)(GBc + w * 7168 + i * 1024 + lc * 64 + grp * 16);
            acc = __builtin_amdgcn_mfma_f32_16x16x32_bf16(af.v, bg, acc, 0, 0, 0);
        }
        if (d < 2) __syncthreads();
    }
    // PV result -> LDS Y planes
    #pragma unroll
    for (int r = 0; r < 4; ++r) {
        int p = grp * 4 + r;
        float v = acc[r];
        ush hh = f2bf(v);
        YH[p][hB] = hh;
        YL[p][hB] = f2bf(v - bf2f(hh));
    }
    __syncthreads();

    // ---- wy: wave w computes out-tiles 2w, 2w+1 ----
    #pragma unroll
    for (int oi = 0; oi < 2; ++oi) {
        int ot = w * 2 + oi;
        const ush* wrH = WwH + (size_t)(ot * 16 + lc) * HC_ + grp * 8;
        const ush* wrL = WwL + (size_t)(ot * 16 + lc) * HC_ + grp * 8;
        f32x4 a2 = {0.f, 0.f, 0.f, 0.f};
        #pragma unroll
        for (int ks = 0; ks < 4; ++ks) {
            bf16x8 bh = *(const bf16x8*)&YH[lc][ks * 32 + grp * 8];
            bf16x8 bl = *(const bf16x8*)&YL[lc][ks * 32 + grp * 8];
            bf16x8 aH = *(const bf16x8*)(wrH + ks * 32);
            bf16x8 aL = *(const bf16x8*)(wrL + ks * 32);
            a2 = __builtin_amdgcn_mfma_f32_16x16x32_bf16(aH, bh, a2, 0, 0, 0);
            a2 = __builtin_amdgcn_mfma_f32_16x16x32_bf16(aH, bl, a2, 0, 0, 0);
            a2 = __builtin_amdgcn_mfma_f32_16x16x32_bf16(aL, bh, a2, 0, 0, 0);
        }
        int o0 = ot * 16 + grp * 4;
        #pragma unroll
        for (int r2 = 0; r2 < 4; ++r2)
            wyO[(size_t)(b * C_ + o0 + r2) * HW_ + pImg + lc] = a2[r2];
    }
}

// ---------------------------------------------------------------------------
// 3) BN batch stats (unchanged)
__global__ __launch_bounds__(256) void bn_stats_kernel(
    const float* __restrict__ wy, const float* __restrict__ gamma,
    const float* __restrict__ beta, float2* __restrict__ stats)
{
    int o = blockIdx.x;
    int tid = threadIdx.x;
    float s = 0.f, s2 = 0.f;
    for (int idx = tid; idx < NP_; idx += 256) {
        int b = idx / HW_;
        int p = idx - b * HW_;
        float v = wy[(size_t)(b * C_ + o) * HW_ + p];
        s += v;
        s2 = fmaf(v, v, s2);
    }
    #pragma unroll
    for (int off = 32; off; off >>= 1) {
        s  += __shfl_xor(s, off);
        s2 += __shfl_xor(s2, off);
    }
    __shared__ float ls[4], ls2[4];
    int wv = tid >> 6, lane = tid & 63;
    if (lane == 0) { ls[wv] = s; ls2[wv] = s2; }
    __syncthreads();
    if (tid == 0) {
        float S  = ls[0] + ls[1] + ls[2] + ls[3];
        float S2 = ls2[0] + ls2[1] + ls2[2] + ls2[3];
        float mean = S / (float)NP_;
        float var = fmaxf(S2 / (float)NP_ - mean * mean, 0.f);
        float rstd = rsqrtf(var + 1e-5f);
        float sc = gamma[o] * rstd;
        stats[o] = make_float2(sc, beta[o] - mean * sc);
    }
}

// ---------------------------------------------------------------------------
// 4) z = x + wy*scale + shift (unchanged)
__global__ __launch_bounds__(256) void final_kernel(
    const float* __restrict__ x, const float* __restrict__ wy,
    const float2* __restrict__ stats, float* __restrict__ out)
{
    int idx = blockIdx.x * 256 + threadIdx.x;
    int e0 = idx * 4;
    int c = (e0 / HW_) & (C_ - 1);
    float2 st = stats[c];
    float4 xv = *(const float4*)(x + e0);
    float4 wv = *(const float4*)(wy + e0);
    float4 o;
    o.x = fmaf(wv.x, st.x, xv.x + st.y);
    o.y = fmaf(wv.y, st.x, xv.y + st.y);
    o.z = fmaf(wv.z, st.x, xv.z + st.y);
    o.w = fmaf(wv.w, st.x, xv.w + st.y);
    *(float4*)(out + e0) = o;
}

extern "C" void kernel_launch(void* const* d_in, const int* in_sizes, int n_in,
                              void* d_out, int out_size, void* d_ws, size_t ws_size,
                              hipStream_t stream) {
    const float* x       = (const float*)d_in[0];
    const float* ctx     = (const float*)d_in[1];
    const float* theta_w = (const float*)d_in[2];
    const float* psi_w   = (const float*)d_in[3];
    const float* g_w     = (const float*)d_in[4];
    const float* W_w     = (const float*)d_in[5];
    // d_in[6] = W_b: unused, cancels exactly under training-mode BN
    const float* gamma   = (const float*)d_in[7];
    const float* beta    = (const float*)d_in[8];
    float* out = (float*)d_out;

    ush* ws = (ush*)d_ws;
    ush* qH    = ws;                     // 589824
    ush* qL    = qH + 589824;
    ush* psiH  = qL + 589824;            // 1769472
    ush* psiL  = psiH + 1769472;
    ush* gB    = psiL + 1769472;         // 2359296  [B,128,3,48,64] padded
    ush* gtmp  = gB + 2359296;           // 3538944  [B,128,3,48,48] unpadded
    ush* WpgH  = gtmp + 3538944;         // 65536
    ush* WpgL  = WpgH + 65536;
    ush* WqH   = WpgL + 65536;           // 32768
    ush* WqL   = WqH + 32768;
    ush* WwH   = WqL + 32768;            // 32768
    ush* WwL   = WwH + 32768;
    ush* ctxTH = WwL + 32768;            // 3538944
    ush* ctxTL = ctxTH + 3538944;
    ush* xTH   = ctxTL + 3538944;        // 1179648
    ush* xTL   = xTH + 1179648;
    float2* stats = (float2*)(xTL + 1179648);
    // alias (stream-ordered single-call lifetime, deterministic each call):
    float* wyB = (float*)ctxTH;          // 1179648 f32 <= ctxT region (proj done)

    prep_kernel<<<dim3(1280), 256, 0, stream>>>(ctx, x, psi_w, g_w, theta_w, W_w,
                                                ctxTH, ctxTL, xTH, xTL,
                                                WpgH, WpgL, WqH, WqL, WwH, WwL);
    proj4_kernel<<<dim3(1008), 256, 0, stream>>>(WpgH, WpgL, WqH, WqL,
                                                 ctxTH, ctxTL, xTH, xTL,
                                                 psiH, psiL, gtmp, qH, qL);
    pad2_kernel<<<dim3(1152), 256, 0, stream>>>(gtmp, gB);
    attn_wy_kernel<<<dim3(288), 512, 143808, stream>>>(qH, qL, psiH, psiL, gB,
                                                       WwH, WwL, wyB);
    bn_stats_kernel<<<dim3(C_), 256, 0, stream>>>(wyB, gamma, beta, stats);
    final_kernel<<<dim3(B_ * C_ * HW_ / 4 / 256), 256, 0, stream>>>(x, wyB, stats, out);
}